// Round 3
// baseline (661.250 us; speedup 1.0000x reference)
//
#include <hip/hip_runtime.h>

// GCN 2-layer forward on gfx950 — CSR-gather, bucketed counting-sort CSR build.
// F=128 in, H=64 hidden, O=10 out. N=100000 nodes, E=1600000 edges.
static constexpr int F = 128;
static constexpr int H = 64;
static constexpr int O = 10;
static constexpr int NBUK_MAX = 256;   // buckets of 512 nodes (dst>>9); N=100k -> 196 used
static constexpr int CAP = 12288;      // per-bucket edge capacity (avg ~8192, sigma ~90)
static constexpr int EPB = 4096;       // edges per block in k_bin

__global__ __launch_bounds__(256) void k_zero_misc(int* __restrict__ bcntg,
                                                   int* __restrict__ cnt, int n) {
    int t = threadIdx.x;
    bcntg[t] = 0;            // 256 entries
    if (t == 0) cnt[n] = 0;  // scan pad entry
}

// Bin edges by bucket = dst>>9. Per-block LDS histogram -> one global atomic
// reservation per (block,bucket) -> bucket-contiguous (src,dst) 8B writes.
__global__ __launch_bounds__(256) void k_bin(const int* __restrict__ src,
                                             const int* __restrict__ dst,
                                             int* __restrict__ bcntg,
                                             uint2* __restrict__ ebuf, int e_total) {
    __shared__ int hist[NBUK_MAX];
    __shared__ int base[NBUK_MAX];
    __shared__ int loc[NBUK_MAX];
    int t = threadIdx.x;
    hist[t] = 0;
    loc[t] = 0;
    __syncthreads();
    int i0 = blockIdx.x * EPB;
    int i1 = min(i0 + EPB, e_total);
    for (int i = i0 + t; i < i1; i += 256) atomicAdd(&hist[dst[i] >> 9], 1);
    __syncthreads();
    if (hist[t] > 0) base[t] = atomicAdd(&bcntg[t], hist[t]);
    __syncthreads();
    for (int i = i0 + t; i < i1; i += 256) {
        int d = dst[i];
        int b = d >> 9;
        int r = base[b] + atomicAdd(&loc[b], 1);
        if (r < CAP) ebuf[(size_t)b * CAP + r] = make_uint2((unsigned)src[i], (unsigned)d);
    }
}

// Per-bucket in-degree count (LDS counters) + dinv. One block per bucket.
__global__ __launch_bounds__(256) void k_bcount(const uint2* __restrict__ ebuf,
                                                const int* __restrict__ bcntg,
                                                int* __restrict__ cnt,
                                                float* __restrict__ dinv, int n_nodes) {
    __shared__ int hc[512];
    int t = threadIdx.x, b = blockIdx.x, n0 = b << 9;
    hc[t] = 0;
    hc[t + 256] = 0;
    __syncthreads();
    int cb = bcntg[b];
    const uint2* eb = ebuf + (size_t)b * CAP;
    for (int i = t; i < cb; i += 256) atomicAdd(&hc[eb[i].y - n0], 1);
    __syncthreads();
#pragma unroll
    for (int u = 0; u < 2; ++u) {
        int n = n0 + t + u * 256;
        if (n < n_nodes) {
            int c = hc[t + u * 256];
            cnt[n] = c;
            dinv[n] = rsqrtf((float)c + 1.0f);   // +1 self-loop
        }
    }
}

// Exclusive scan of cnt[0..n) (n = N+1 entries) -> rowptr, per-256 block + bsum.
__global__ __launch_bounds__(256) void k_scan1(const int* __restrict__ cnt,
                                               int* __restrict__ rowptr,
                                               int* __restrict__ bsum, int n) {
    __shared__ int s[256];
    int t = threadIdx.x;
    int i = blockIdx.x * 256 + t;
    int v = (i < n) ? cnt[i] : 0;
    s[t] = v;
    __syncthreads();
    for (int off = 1; off < 256; off <<= 1) {
        int x = (t >= off) ? s[t - off] : 0;
        __syncthreads();
        s[t] += x;
        __syncthreads();
    }
    if (i < n) rowptr[i] = s[t] - v;
    if (t == 255) bsum[blockIdx.x] = s[255];
}

__global__ __launch_bounds__(512) void k_scan2(int* __restrict__ bsum, int nb) {
    __shared__ int s[512];
    int t = threadIdx.x;
    int v = (t < nb) ? bsum[t] : 0;
    s[t] = v;
    __syncthreads();
    for (int off = 1; off < 512; off <<= 1) {
        int x = (t >= off) ? s[t - off] : 0;
        __syncthreads();
        s[t] += x;
        __syncthreads();
    }
    if (t < nb) bsum[t] = s[t] - v;
}

__global__ __launch_bounds__(256) void k_scan3(int* __restrict__ rowptr,
                                               const int* __restrict__ bsum, int n) {
    int i = blockIdx.x * 256 + threadIdx.x;
    if (i < n) rowptr[i] += bsum[blockIdx.x];
}

// Per-bucket CSR fill: LDS cursors, esrc writes confined to one ~34KB window per CU.
__global__ __launch_bounds__(256) void k_fillb(const uint2* __restrict__ ebuf,
                                               const int* __restrict__ bcntg,
                                               const int* __restrict__ rowptr,
                                               int* __restrict__ esrc, int n_nodes) {
    __shared__ int curs[512];
    int t = threadIdx.x, b = blockIdx.x, n0 = b << 9;
#pragma unroll
    for (int u = 0; u < 2; ++u) {
        int n = n0 + t + u * 256;
        if (n < n_nodes) curs[t + u * 256] = rowptr[n];
    }
    __syncthreads();
    int cb = bcntg[b];
    const uint2* eb = ebuf + (size_t)b * CAP;
    for (int i = t; i < cb; i += 256) {
        uint2 e = eb[i];
        int r = atomicAdd(&curs[e.y - n0], 1);
        esrc[r] = (int)e.x;
    }
}

// y[n][j] = (x @ W1)[n][j] * dinv[n].  Wave = 64 j-lanes; W1 column staged in
// 128 VGPRs per lane; per node: 32 uniform float4 x-loads + 128 FMAs (4 chains).
__global__ __launch_bounds__(256, 2) void k_gemm1(
    const float* __restrict__ x, const float* __restrict__ W1,
    const float* __restrict__ dinv, float* __restrict__ y, int n_nodes) {
    const int j = threadIdx.x & 63;
    const int gw = blockIdx.x * 4 + (threadIdx.x >> 6);
    const int nw = gridDim.x * 4;
    float w[F];
#pragma unroll
    for (int k = 0; k < F; ++k) w[k] = W1[k * H + j];
    for (int n = gw; n < n_nodes; n += nw) {
        const float4* xr = (const float4*)(x + (size_t)n * F);
        float a0 = 0.f, a1 = 0.f, a2 = 0.f, a3 = 0.f;
#pragma unroll
        for (int k4 = 0; k4 < F / 4; ++k4) {
            float4 xv = xr[k4];
            a0 = fmaf(xv.x, w[4 * k4 + 0], a0);
            a1 = fmaf(xv.y, w[4 * k4 + 1], a1);
            a2 = fmaf(xv.z, w[4 * k4 + 2], a2);
            a3 = fmaf(xv.w, w[4 * k4 + 3], a3);
        }
        y[(size_t)n * H + j] = ((a0 + a1) + (a2 + a3)) * dinv[n];
    }
}

// h[n][j] = relu(dinv[n] * (y[n][j] + sum_{k in row} y[esrc[k]][j]) + b1[j])
__global__ __launch_bounds__(256) void k_gather1(
    const float* __restrict__ y, const int* __restrict__ rowptr,
    const int* __restrict__ esrc, const float* __restrict__ dinv,
    const float* __restrict__ b1, float* __restrict__ h, int n_nodes) {
    const int j = threadIdx.x & 63;
    const int n = blockIdx.x * 4 + (threadIdx.x >> 6);
    if (n >= n_nodes) return;
    int beg = rowptr[n], end = rowptr[n + 1];
    float acc = y[(size_t)n * H + j];
    int k = beg;
    for (; k + 3 < end; k += 4) {
        int s0 = esrc[k], s1 = esrc[k + 1], s2 = esrc[k + 2], s3 = esrc[k + 3];
        float v0 = y[(size_t)s0 * H + j];
        float v1 = y[(size_t)s1 * H + j];
        float v2 = y[(size_t)s2 * H + j];
        float v3 = y[(size_t)s3 * H + j];
        acc += (v0 + v1) + (v2 + v3);
    }
    for (; k < end; ++k) acc += y[(size_t)esrc[k] * H + j];
    h[(size_t)n * H + j] = fmaxf(fmaf(dinv[n], acc, b1[j]), 0.0f);
}

// zs[n][j] = dinv[n] * (h[n] @ W2)[j]   — wave per node, shuffle reduction.
__global__ __launch_bounds__(256) void k_zs(
    const float* __restrict__ h, const float* __restrict__ W2,
    const float* __restrict__ dinv, float* __restrict__ zs, int n_nodes) {
    const int l = threadIdx.x & 63;
    const int n = blockIdx.x * 4 + (threadIdx.x >> 6);
    if (n >= n_nodes) return;
    float hv = h[(size_t)n * H + l];
    const float d = dinv[n];
#pragma unroll
    for (int j = 0; j < O; ++j) {
        float v = hv * W2[l * O + j];
#pragma unroll
        for (int off = 32; off > 0; off >>= 1) v += __shfl_xor(v, off, 64);
        if (l == j) zs[(size_t)n * O + j] = v * d;
    }
}

// out[n][j] = dinv[n] * (zs[n][j] + sum_{k in row} zs[esrc[k]][j]) + b2[j]
__global__ __launch_bounds__(256) void k_gather2(
    const float* __restrict__ zs, const int* __restrict__ rowptr,
    const int* __restrict__ esrc, const float* __restrict__ dinv,
    const float* __restrict__ b2, float* __restrict__ out, int n_nodes) {
    const int j = threadIdx.x & 15;
    const int n = blockIdx.x * 16 + (threadIdx.x >> 4);
    if (n >= n_nodes || j >= O) return;
    int beg = rowptr[n], end = rowptr[n + 1];
    float acc = zs[(size_t)n * O + j];
    int k = beg;
    for (; k + 1 < end; k += 2) {
        int s0 = esrc[k], s1 = esrc[k + 1];
        acc += zs[(size_t)s0 * O + j] + zs[(size_t)s1 * O + j];
    }
    for (; k < end; ++k) acc += zs[(size_t)esrc[k] * O + j];
    out[(size_t)n * O + j] = fmaf(dinv[n], acc, b2[j]);
}

extern "C" void kernel_launch(void* const* d_in, const int* in_sizes, int n_in,
                              void* d_out, int out_size, void* d_ws, size_t ws_size,
                              hipStream_t stream) {
    const float* x  = (const float*)d_in[0];
    const int*   ei = (const int*)d_in[1];
    const float* W1 = (const float*)d_in[2];
    const float* b1 = (const float*)d_in[3];
    const float* W2 = (const float*)d_in[4];
    const float* b2 = (const float*)d_in[5];
    float* out = (float*)d_out;

    const int N = in_sizes[0] / F;   // 100000
    const int E = in_sizes[1] / 2;   // 1600000
    const int* src = ei;
    const int* dst = ei + E;

    // Workspace: y[N*H] | h[N*H] (aliased: ebuf uint2[NBUK*CAP] = 19.3MB <= 25.6MB)
    //          | zs[N*O] | dinv[N] | cnt[N+1] | rowptr[N+1] | bsum[512]
    //          | bcntg[256] | esrc[E]
    float* y    = (float*)d_ws;
    float* h    = y + (size_t)N * H;
    uint2* ebuf = (uint2*)h;               // consumed before h is written
    float* zs   = h + (size_t)N * H;
    float* dinv = zs + (size_t)N * O;
    int* cnt    = (int*)(dinv + N);
    int* rowptr = cnt + (N + 1);
    int* bsum   = rowptr + (N + 1);
    int* bcntg  = bsum + 512;
    int* esrc   = bcntg + 256;

    const int NBUK  = (N + 511) >> 9;          // 196
    const int nb_n1 = (N + 256) / 256;         // covers N+1 entries (391 <= 512)
    const int nb_bin = (E + EPB - 1) / EPB;    // 391

    k_zero_misc<<<1, 256, 0, stream>>>(bcntg, cnt, N);
    k_bin<<<nb_bin, 256, 0, stream>>>(src, dst, bcntg, ebuf, E);
    k_bcount<<<NBUK, 256, 0, stream>>>(ebuf, bcntg, cnt, dinv, N);
    k_scan1<<<nb_n1, 256, 0, stream>>>(cnt, rowptr, bsum, N + 1);
    k_scan2<<<1, 512, 0, stream>>>(bsum, nb_n1);
    k_scan3<<<nb_n1, 256, 0, stream>>>(rowptr, bsum, N + 1);
    k_fillb<<<NBUK, 256, 0, stream>>>(ebuf, bcntg, rowptr, esrc, N);
    k_gemm1<<<512, 256, 0, stream>>>(x, W1, dinv, y, N);
    k_gather1<<<(N + 3) / 4, 256, 0, stream>>>(y, rowptr, esrc, dinv, b1, h, N);
    k_zs<<<(N + 3) / 4, 256, 0, stream>>>(h, W2, dinv, zs, N);
    k_gather2<<<(N + 15) / 16, 256, 0, stream>>>(zs, rowptr, esrc, dinv, b2, out, N);
}

// Round 4
// 358.856 us; speedup vs baseline: 1.8427x; 1.8427x over previous
//
#include <hip/hip_runtime.h>

// GCN 2-layer forward on gfx950 — CSR-gather, bucketed counting-sort CSR build,
// LDS-tiled fp32 GEMM for layer-1 transform.
// F=128 in, H=64 hidden, O=10 out. N=100000 nodes, E=1600000 edges.
static constexpr int F = 128;
static constexpr int H = 64;
static constexpr int O = 10;
static constexpr int NBUK_MAX = 256;   // buckets of 512 nodes (dst>>9); N=100k -> 196 used
static constexpr int CAP = 12288;      // per-bucket edge capacity (avg ~8192)
static constexpr int EPB = 4096;       // edges per block in k_bin
static constexpr int TS = 132;         // bt LDS stride (128 + 4 pad)
static constexpr int XS = 68;          // xs LDS stride (64 + 4 pad)

__global__ __launch_bounds__(256) void k_zero_misc(int* __restrict__ bcntg,
                                                   int* __restrict__ cnt, int n) {
    int t = threadIdx.x;
    bcntg[t] = 0;            // 256 entries
    if (t == 0) cnt[n] = 0;  // scan pad entry
}

// Bin edges by bucket = dst>>9. Per-block LDS histogram -> one global atomic
// reservation per (block,bucket) -> bucket-contiguous (src,dst) 8B writes.
__global__ __launch_bounds__(256) void k_bin(const int* __restrict__ src,
                                             const int* __restrict__ dst,
                                             int* __restrict__ bcntg,
                                             uint2* __restrict__ ebuf, int e_total) {
    __shared__ int hist[NBUK_MAX];
    __shared__ int base[NBUK_MAX];
    __shared__ int loc[NBUK_MAX];
    int t = threadIdx.x;
    hist[t] = 0;
    loc[t] = 0;
    __syncthreads();
    int i0 = blockIdx.x * EPB;
    int i1 = min(i0 + EPB, e_total);
    for (int i = i0 + t; i < i1; i += 256) atomicAdd(&hist[dst[i] >> 9], 1);
    __syncthreads();
    if (hist[t] > 0) base[t] = atomicAdd(&bcntg[t], hist[t]);
    __syncthreads();
    for (int i = i0 + t; i < i1; i += 256) {
        int d = dst[i];
        int b = d >> 9;
        int r = base[b] + atomicAdd(&loc[b], 1);
        if (r < CAP) ebuf[(size_t)b * CAP + r] = make_uint2((unsigned)src[i], (unsigned)d);
    }
}

// Per-bucket in-degree count (LDS counters) + dinv. One block per bucket.
__global__ __launch_bounds__(256) void k_bcount(const uint2* __restrict__ ebuf,
                                                const int* __restrict__ bcntg,
                                                int* __restrict__ cnt,
                                                float* __restrict__ dinv, int n_nodes) {
    __shared__ int hc[512];
    int t = threadIdx.x, b = blockIdx.x, n0 = b << 9;
    hc[t] = 0;
    hc[t + 256] = 0;
    __syncthreads();
    int cb = bcntg[b];
    const uint2* eb = ebuf + (size_t)b * CAP;
    for (int i = t; i < cb; i += 256) atomicAdd(&hc[eb[i].y - n0], 1);
    __syncthreads();
#pragma unroll
    for (int u = 0; u < 2; ++u) {
        int n = n0 + t + u * 256;
        if (n < n_nodes) {
            int c = hc[t + u * 256];
            cnt[n] = c;
            dinv[n] = rsqrtf((float)c + 1.0f);   // +1 self-loop
        }
    }
}

// Exclusive scan of cnt[0..n) (n = N+1 entries) -> rowptr, per-256 block + bsum.
__global__ __launch_bounds__(256) void k_scan1(const int* __restrict__ cnt,
                                               int* __restrict__ rowptr,
                                               int* __restrict__ bsum, int n) {
    __shared__ int s[256];
    int t = threadIdx.x;
    int i = blockIdx.x * 256 + t;
    int v = (i < n) ? cnt[i] : 0;
    s[t] = v;
    __syncthreads();
    for (int off = 1; off < 256; off <<= 1) {
        int x = (t >= off) ? s[t - off] : 0;
        __syncthreads();
        s[t] += x;
        __syncthreads();
    }
    if (i < n) rowptr[i] = s[t] - v;
    if (t == 255) bsum[blockIdx.x] = s[255];
}

__global__ __launch_bounds__(512) void k_scan2(int* __restrict__ bsum, int nb) {
    __shared__ int s[512];
    int t = threadIdx.x;
    int v = (t < nb) ? bsum[t] : 0;
    s[t] = v;
    __syncthreads();
    for (int off = 1; off < 512; off <<= 1) {
        int x = (t >= off) ? s[t - off] : 0;
        __syncthreads();
        s[t] += x;
        __syncthreads();
    }
    if (t < nb) bsum[t] = s[t] - v;
}

__global__ __launch_bounds__(256) void k_scan3(int* __restrict__ rowptr,
                                               const int* __restrict__ bsum, int n) {
    int i = blockIdx.x * 256 + threadIdx.x;
    if (i < n) rowptr[i] += bsum[blockIdx.x];
}

// Per-bucket CSR fill: LDS cursors, esrc writes confined to one ~34KB window per CU.
__global__ __launch_bounds__(256) void k_fillb(const uint2* __restrict__ ebuf,
                                               const int* __restrict__ bcntg,
                                               const int* __restrict__ rowptr,
                                               int* __restrict__ esrc, int n_nodes) {
    __shared__ int curs[512];
    int t = threadIdx.x, b = blockIdx.x, n0 = b << 9;
#pragma unroll
    for (int u = 0; u < 2; ++u) {
        int n = n0 + t + u * 256;
        if (n < n_nodes) curs[t + u * 256] = rowptr[n];
    }
    __syncthreads();
    int cb = bcntg[b];
    const uint2* eb = ebuf + (size_t)b * CAP;
    for (int i = t; i < cb; i += 256) {
        uint2 e = eb[i];
        int r = atomicAdd(&curs[e.y - n0], 1);
        esrc[r] = (int)e.x;
    }
}

// W1t[c][k] = W1[k][c]  (one-time 32KB transpose so gemm1 staging is a pure copy)
__global__ __launch_bounds__(256) void k_wt(const float* __restrict__ W1,
                                            float* __restrict__ W1t) {
    int t = blockIdx.x * 256 + threadIdx.x;
    if (t < F * H) {
        int k = t >> 6, c = t & 63;
        W1t[c * F + k] = W1[k * H + c];
    }
}

// y = (x @ W1) * dinv[n], LDS-tiled: 64-row tiles, W1^T resident in LDS,
// per-thread 4x4 register tile (rows/cols strided by 16 -> <=2-way LDS aliasing).
__global__ __launch_bounds__(256) void k_gemm1(
    const float* __restrict__ x, const float* __restrict__ W1t,
    const float* __restrict__ dinv, float* __restrict__ y, int n_nodes) {
    __shared__ float bt[H * TS];   // [col][k], 33792 B
    __shared__ float xs[64 * XS];  // [row][k-half], 17408 B
    const int tid = threadIdx.x;
    const int rg = tid >> 4;       // 0..15
    const int cg = tid & 15;       // 0..15
    const int row0 = blockIdx.x * 64;

    // stage W1t -> bt (coalesced float4 copy, conflict-free b128 writes)
    for (int i = tid; i < H * (F / 4); i += 256) {
        int c = i >> 5, k4 = i & 31;
        float4 v = *(const float4*)&W1t[c * F + 4 * k4];
        *(float4*)&bt[c * TS + 4 * k4] = v;
    }

    float acc[4][4];
#pragma unroll
    for (int i = 0; i < 4; ++i)
#pragma unroll
        for (int j = 0; j < 4; ++j) acc[i][j] = 0.f;

    for (int kh = 0; kh < 2; ++kh) {
        __syncthreads();
        // stage x[row0..row0+63][64kh..64kh+63] -> xs
        for (int i = tid; i < 64 * 16; i += 256) {
            int r = i >> 4, k4 = i & 15;
            int gr = row0 + r;
            float4 v = (gr < n_nodes)
                           ? *(const float4*)&x[(size_t)gr * F + kh * 64 + 4 * k4]
                           : make_float4(0.f, 0.f, 0.f, 0.f);
            *(float4*)&xs[r * XS + 4 * k4] = v;
        }
        __syncthreads();
#pragma unroll
        for (int k4 = 0; k4 < 16; ++k4) {
            float4 a[4], b[4];
#pragma unroll
            for (int c = 0; c < 4; ++c)
                a[c] = *(const float4*)&xs[(rg + 16 * c) * XS + 4 * k4];
#pragma unroll
            for (int c = 0; c < 4; ++c)
                b[c] = *(const float4*)&bt[(cg + 16 * c) * TS + kh * 64 + 4 * k4];
#pragma unroll
            for (int i = 0; i < 4; ++i)
#pragma unroll
                for (int j = 0; j < 4; ++j) {
                    acc[i][j] = fmaf(a[i].x, b[j].x, acc[i][j]);
                    acc[i][j] = fmaf(a[i].y, b[j].y, acc[i][j]);
                    acc[i][j] = fmaf(a[i].z, b[j].z, acc[i][j]);
                    acc[i][j] = fmaf(a[i].w, b[j].w, acc[i][j]);
                }
        }
    }
#pragma unroll
    for (int i = 0; i < 4; ++i) {
        int r = row0 + rg + 16 * i;
        if (r < n_nodes) {
            float d = dinv[r];
#pragma unroll
            for (int j = 0; j < 4; ++j)
                y[(size_t)r * H + cg + 16 * j] = acc[i][j] * d;
        }
    }
}

// h[n][j] = relu(dinv[n] * (y[n][j] + sum_{k in row} y[esrc[k]][j]) + b1[j])
__global__ __launch_bounds__(256) void k_gather1(
    const float* __restrict__ y, const int* __restrict__ rowptr,
    const int* __restrict__ esrc, const float* __restrict__ dinv,
    const float* __restrict__ b1, float* __restrict__ h, int n_nodes) {
    const int j = threadIdx.x & 63;
    const int n = blockIdx.x * 4 + (threadIdx.x >> 6);
    if (n >= n_nodes) return;
    int beg = rowptr[n], end = rowptr[n + 1];
    float acc = y[(size_t)n * H + j];
    int k = beg;
    for (; k + 3 < end; k += 4) {
        int s0 = esrc[k], s1 = esrc[k + 1], s2 = esrc[k + 2], s3 = esrc[k + 3];
        float v0 = y[(size_t)s0 * H + j];
        float v1 = y[(size_t)s1 * H + j];
        float v2 = y[(size_t)s2 * H + j];
        float v3 = y[(size_t)s3 * H + j];
        acc += (v0 + v1) + (v2 + v3);
    }
    for (; k < end; ++k) acc += y[(size_t)esrc[k] * H + j];
    h[(size_t)n * H + j] = fmaxf(fmaf(dinv[n], acc, b1[j]), 0.0f);
}

// zs[n][j] = dinv[n] * (h[n] @ W2)[j]   — wave per node, shuffle reduction.
__global__ __launch_bounds__(256) void k_zs(
    const float* __restrict__ h, const float* __restrict__ W2,
    const float* __restrict__ dinv, float* __restrict__ zs, int n_nodes) {
    const int l = threadIdx.x & 63;
    const int n = blockIdx.x * 4 + (threadIdx.x >> 6);
    if (n >= n_nodes) return;
    float hv = h[(size_t)n * H + l];
    const float d = dinv[n];
#pragma unroll
    for (int j = 0; j < O; ++j) {
        float v = hv * W2[l * O + j];
#pragma unroll
        for (int off = 32; off > 0; off >>= 1) v += __shfl_xor(v, off, 64);
        if (l == j) zs[(size_t)n * O + j] = v * d;
    }
}

// out[n][j] = dinv[n] * (zs[n][j] + sum_{k in row} zs[esrc[k]][j]) + b2[j]
__global__ __launch_bounds__(256) void k_gather2(
    const float* __restrict__ zs, const int* __restrict__ rowptr,
    const int* __restrict__ esrc, const float* __restrict__ dinv,
    const float* __restrict__ b2, float* __restrict__ out, int n_nodes) {
    const int j = threadIdx.x & 15;
    const int n = blockIdx.x * 16 + (threadIdx.x >> 4);
    if (n >= n_nodes || j >= O) return;
    int beg = rowptr[n], end = rowptr[n + 1];
    float acc = zs[(size_t)n * O + j];
    int k = beg;
    for (; k + 1 < end; k += 2) {
        int s0 = esrc[k], s1 = esrc[k + 1];
        acc += zs[(size_t)s0 * O + j] + zs[(size_t)s1 * O + j];
    }
    for (; k < end; ++k) acc += zs[(size_t)esrc[k] * O + j];
    out[(size_t)n * O + j] = fmaf(dinv[n], acc, b2[j]);
}

extern "C" void kernel_launch(void* const* d_in, const int* in_sizes, int n_in,
                              void* d_out, int out_size, void* d_ws, size_t ws_size,
                              hipStream_t stream) {
    const float* x  = (const float*)d_in[0];
    const int*   ei = (const int*)d_in[1];
    const float* W1 = (const float*)d_in[2];
    const float* b1 = (const float*)d_in[3];
    const float* W2 = (const float*)d_in[4];
    const float* b2 = (const float*)d_in[5];
    float* out = (float*)d_out;

    const int N = in_sizes[0] / F;   // 100000
    const int E = in_sizes[1] / 2;   // 1600000
    const int* src = ei;
    const int* dst = ei + E;

    // Workspace: y[N*H] | h[N*H] (front aliased by ebuf 19.3MB; tail 32KB holds W1t)
    //          | zs[N*O] | dinv[N] | cnt[N+1] | rowptr[N+1] | bsum[512]
    //          | bcntg[256] | esrc[E]
    float* y    = (float*)d_ws;
    float* h    = y + (size_t)N * H;
    uint2* ebuf = (uint2*)h;                       // consumed before h is written
    float* W1t  = h + (size_t)N * H - F * H;       // tail of h region, after ebuf
    float* zs   = h + (size_t)N * H;
    float* dinv = zs + (size_t)N * O;
    int* cnt    = (int*)(dinv + N);
    int* rowptr = cnt + (N + 1);
    int* bsum   = rowptr + (N + 1);
    int* bcntg  = bsum + 512;
    int* esrc   = bcntg + 256;

    const int NBUK   = (N + 511) >> 9;          // 196
    const int nb_n1  = (N + 256) / 256;         // covers N+1 entries (391 <= 512)
    const int nb_bin = (E + EPB - 1) / EPB;     // 391

    k_zero_misc<<<1, 256, 0, stream>>>(bcntg, cnt, N);
    k_wt<<<(F * H + 255) / 256, 256, 0, stream>>>(W1, W1t);
    k_bin<<<nb_bin, 256, 0, stream>>>(src, dst, bcntg, ebuf, E);
    k_bcount<<<NBUK, 256, 0, stream>>>(ebuf, bcntg, cnt, dinv, N);
    k_scan1<<<nb_n1, 256, 0, stream>>>(cnt, rowptr, bsum, N + 1);
    k_scan2<<<1, 512, 0, stream>>>(bsum, nb_n1);
    k_scan3<<<nb_n1, 256, 0, stream>>>(rowptr, bsum, N + 1);
    k_fillb<<<NBUK, 256, 0, stream>>>(ebuf, bcntg, rowptr, esrc, N);
    k_gemm1<<<(N + 63) / 64, 256, 0, stream>>>(x, W1t, dinv, y, N);
    k_gather1<<<(N + 3) / 4, 256, 0, stream>>>(y, rowptr, esrc, dinv, b1, h, N);
    k_zs<<<(N + 3) / 4, 256, 0, stream>>>(h, W2, dinv, zs, N);
    k_gather2<<<(N + 15) / 16, 256, 0, stream>>>(zs, rowptr, esrc, dinv, b2, out, N);
}

// Round 5
// 294.732 us; speedup vs baseline: 2.2436x; 1.2176x over previous
//
#include <hip/hip_runtime.h>

// GCN 2-layer forward on gfx950 — CSR-gather, bucketed counting-sort CSR build,
// LDS-tiled fp32 GEMM for layer-1 transform, thread-per-node layer-2 matvec.
// F=128 in, H=64 hidden, O=10 out. N=100000 nodes, E=1600000 edges.
static constexpr int F = 128;
static constexpr int H = 64;
static constexpr int O = 10;
static constexpr int NBUK_MAX = 256;   // buckets of 512 nodes (dst>>9); N=100k -> 196 used
static constexpr int CAP = 12288;      // per-bucket edge capacity (avg ~8192)
static constexpr int EPB = 4096;       // edges per block in k_bin
static constexpr int TS = 132;         // bt LDS stride (128 + 4 pad)
static constexpr int XS = 68;          // xs LDS stride (64 + 4 pad)

__global__ __launch_bounds__(256) void k_zero_misc(int* __restrict__ bcntg,
                                                   int* __restrict__ cnt, int n) {
    int t = threadIdx.x;
    bcntg[t] = 0;            // 256 entries
    if (t == 0) cnt[n] = 0;  // scan pad entry
}

// Bin edges by bucket = dst>>9. Per-block LDS histogram -> one global atomic
// reservation per (block,bucket) -> bucket-contiguous (src,dst) 8B writes.
__global__ __launch_bounds__(256) void k_bin(const int* __restrict__ src,
                                             const int* __restrict__ dst,
                                             int* __restrict__ bcntg,
                                             uint2* __restrict__ ebuf, int e_total) {
    __shared__ int hist[NBUK_MAX];
    __shared__ int base[NBUK_MAX];
    __shared__ int loc[NBUK_MAX];
    int t = threadIdx.x;
    hist[t] = 0;
    loc[t] = 0;
    __syncthreads();
    int i0 = blockIdx.x * EPB;
    int i1 = min(i0 + EPB, e_total);
    for (int i = i0 + t; i < i1; i += 256) atomicAdd(&hist[dst[i] >> 9], 1);
    __syncthreads();
    if (hist[t] > 0) base[t] = atomicAdd(&bcntg[t], hist[t]);
    __syncthreads();
    for (int i = i0 + t; i < i1; i += 256) {
        int d = dst[i];
        int b = d >> 9;
        int r = base[b] + atomicAdd(&loc[b], 1);
        if (r < CAP) ebuf[(size_t)b * CAP + r] = make_uint2((unsigned)src[i], (unsigned)d);
    }
}

// Per-bucket in-degree count (LDS counters) + dinv. One block per bucket.
__global__ __launch_bounds__(256) void k_bcount(const uint2* __restrict__ ebuf,
                                                const int* __restrict__ bcntg,
                                                int* __restrict__ cnt,
                                                float* __restrict__ dinv, int n_nodes) {
    __shared__ int hc[512];
    int t = threadIdx.x, b = blockIdx.x, n0 = b << 9;
    hc[t] = 0;
    hc[t + 256] = 0;
    __syncthreads();
    int cb = bcntg[b];
    const uint2* eb = ebuf + (size_t)b * CAP;
    for (int i = t; i < cb; i += 256) atomicAdd(&hc[eb[i].y - n0], 1);
    __syncthreads();
#pragma unroll
    for (int u = 0; u < 2; ++u) {
        int n = n0 + t + u * 256;
        if (n < n_nodes) {
            int c = hc[t + u * 256];
            cnt[n] = c;
            dinv[n] = rsqrtf((float)c + 1.0f);   // +1 self-loop
        }
    }
}

// Exclusive scan of cnt[0..n) (n = N+1 entries) -> rowptr, per-256 block + bsum.
__global__ __launch_bounds__(256) void k_scan1(const int* __restrict__ cnt,
                                               int* __restrict__ rowptr,
                                               int* __restrict__ bsum, int n) {
    __shared__ int s[256];
    int t = threadIdx.x;
    int i = blockIdx.x * 256 + t;
    int v = (i < n) ? cnt[i] : 0;
    s[t] = v;
    __syncthreads();
    for (int off = 1; off < 256; off <<= 1) {
        int x = (t >= off) ? s[t - off] : 0;
        __syncthreads();
        s[t] += x;
        __syncthreads();
    }
    if (i < n) rowptr[i] = s[t] - v;
    if (t == 255) bsum[blockIdx.x] = s[255];
}

__global__ __launch_bounds__(512) void k_scan2(int* __restrict__ bsum, int nb) {
    __shared__ int s[512];
    int t = threadIdx.x;
    int v = (t < nb) ? bsum[t] : 0;
    s[t] = v;
    __syncthreads();
    for (int off = 1; off < 512; off <<= 1) {
        int x = (t >= off) ? s[t - off] : 0;
        __syncthreads();
        s[t] += x;
        __syncthreads();
    }
    if (t < nb) bsum[t] = s[t] - v;
}

__global__ __launch_bounds__(256) void k_scan3(int* __restrict__ rowptr,
                                               const int* __restrict__ bsum, int n) {
    int i = blockIdx.x * 256 + threadIdx.x;
    if (i < n) rowptr[i] += bsum[blockIdx.x];
}

// Per-bucket CSR fill: LDS cursors, esrc writes confined to one ~34KB window per CU.
__global__ __launch_bounds__(256) void k_fillb(const uint2* __restrict__ ebuf,
                                               const int* __restrict__ bcntg,
                                               const int* __restrict__ rowptr,
                                               int* __restrict__ esrc, int n_nodes) {
    __shared__ int curs[512];
    int t = threadIdx.x, b = blockIdx.x, n0 = b << 9;
#pragma unroll
    for (int u = 0; u < 2; ++u) {
        int n = n0 + t + u * 256;
        if (n < n_nodes) curs[t + u * 256] = rowptr[n];
    }
    __syncthreads();
    int cb = bcntg[b];
    const uint2* eb = ebuf + (size_t)b * CAP;
    for (int i = t; i < cb; i += 256) {
        uint2 e = eb[i];
        int r = atomicAdd(&curs[e.y - n0], 1);
        esrc[r] = (int)e.x;
    }
}

// W1t[c][k] = W1[k][c]  (one-time 32KB transpose so gemm1 staging is a pure copy)
__global__ __launch_bounds__(256) void k_wt(const float* __restrict__ W1,
                                            float* __restrict__ W1t) {
    int t = blockIdx.x * 256 + threadIdx.x;
    if (t < F * H) {
        int k = t >> 6, c = t & 63;
        W1t[c * F + k] = W1[k * H + c];
    }
}

// y = (x @ W1) * dinv[n], LDS-tiled: 64-row tiles, W1^T resident in LDS,
// per-thread 4x4 register tile (rows/cols strided by 16 -> <=2-way LDS aliasing).
__global__ __launch_bounds__(256) void k_gemm1(
    const float* __restrict__ x, const float* __restrict__ W1t,
    const float* __restrict__ dinv, float* __restrict__ y, int n_nodes) {
    __shared__ float bt[H * TS];   // [col][k], 33792 B
    __shared__ float xs[64 * XS];  // [row][k-half], 17408 B
    const int tid = threadIdx.x;
    const int rg = tid >> 4;       // 0..15
    const int cg = tid & 15;       // 0..15
    const int row0 = blockIdx.x * 64;

    for (int i = tid; i < H * (F / 4); i += 256) {
        int c = i >> 5, k4 = i & 31;
        float4 v = *(const float4*)&W1t[c * F + 4 * k4];
        *(float4*)&bt[c * TS + 4 * k4] = v;
    }

    float acc[4][4];
#pragma unroll
    for (int i = 0; i < 4; ++i)
#pragma unroll
        for (int j = 0; j < 4; ++j) acc[i][j] = 0.f;

    for (int kh = 0; kh < 2; ++kh) {
        __syncthreads();
        for (int i = tid; i < 64 * 16; i += 256) {
            int r = i >> 4, k4 = i & 15;
            int gr = row0 + r;
            float4 v = (gr < n_nodes)
                           ? *(const float4*)&x[(size_t)gr * F + kh * 64 + 4 * k4]
                           : make_float4(0.f, 0.f, 0.f, 0.f);
            *(float4*)&xs[r * XS + 4 * k4] = v;
        }
        __syncthreads();
#pragma unroll
        for (int k4 = 0; k4 < 16; ++k4) {
            float4 a[4], b[4];
#pragma unroll
            for (int c = 0; c < 4; ++c)
                a[c] = *(const float4*)&xs[(rg + 16 * c) * XS + 4 * k4];
#pragma unroll
            for (int c = 0; c < 4; ++c)
                b[c] = *(const float4*)&bt[(cg + 16 * c) * TS + kh * 64 + 4 * k4];
#pragma unroll
            for (int i = 0; i < 4; ++i)
#pragma unroll
                for (int j = 0; j < 4; ++j) {
                    acc[i][j] = fmaf(a[i].x, b[j].x, acc[i][j]);
                    acc[i][j] = fmaf(a[i].y, b[j].y, acc[i][j]);
                    acc[i][j] = fmaf(a[i].z, b[j].z, acc[i][j]);
                    acc[i][j] = fmaf(a[i].w, b[j].w, acc[i][j]);
                }
        }
    }
#pragma unroll
    for (int i = 0; i < 4; ++i) {
        int r = row0 + rg + 16 * i;
        if (r < n_nodes) {
            float d = dinv[r];
#pragma unroll
            for (int j = 0; j < 4; ++j)
                y[(size_t)r * H + cg + 16 * j] = acc[i][j] * d;
        }
    }
}

// h[n][j] = relu(dinv[n] * (y[n][j] + sum_{k in row} y[esrc[k]][j]) + b1[j])
__global__ __launch_bounds__(256) void k_gather1(
    const float* __restrict__ y, const int* __restrict__ rowptr,
    const int* __restrict__ esrc, const float* __restrict__ dinv,
    const float* __restrict__ b1, float* __restrict__ h, int n_nodes) {
    const int j = threadIdx.x & 63;
    const int n = blockIdx.x * 4 + (threadIdx.x >> 6);
    if (n >= n_nodes) return;
    int beg = rowptr[n], end = rowptr[n + 1];
    float acc = y[(size_t)n * H + j];
    int k = beg;
    for (; k + 3 < end; k += 4) {
        int s0 = esrc[k], s1 = esrc[k + 1], s2 = esrc[k + 2], s3 = esrc[k + 3];
        float v0 = y[(size_t)s0 * H + j];
        float v1 = y[(size_t)s1 * H + j];
        float v2 = y[(size_t)s2 * H + j];
        float v3 = y[(size_t)s3 * H + j];
        acc += (v0 + v1) + (v2 + v3);
    }
    for (; k < end; ++k) acc += y[(size_t)esrc[k] * H + j];
    h[(size_t)n * H + j] = fmaxf(fmaf(dinv[n], acc, b1[j]), 0.0f);
}

// zs[n][j] = dinv[n] * (h[n] @ W2)[j].  Thread per node: h row via 16 float4,
// W2 at compile-time-constant offsets -> wave-uniform s_load (SMEM pipe),
// results staged in LDS for fully-coalesced output writes.
__global__ __launch_bounds__(256) void k_zs(
    const float* __restrict__ h, const float* __restrict__ W2,
    const float* __restrict__ dinv, float* __restrict__ zs, int n_nodes) {
    __shared__ float zbuf[256 * O];     // 10 KB
    const int t = threadIdx.x;
    const int n0 = blockIdx.x * 256;
    const int n = n0 + t;
    if (n < n_nodes) {
        float acc[O];
#pragma unroll
        for (int j = 0; j < O; ++j) acc[j] = 0.f;
        const float4* hr = (const float4*)(h + (size_t)n * H);
#pragma unroll
        for (int k4 = 0; k4 < H / 4; ++k4) {
            float4 hv = hr[k4];
#pragma unroll
            for (int j = 0; j < O; ++j) {
                acc[j] = fmaf(hv.x, W2[(4 * k4 + 0) * O + j], acc[j]);
                acc[j] = fmaf(hv.y, W2[(4 * k4 + 1) * O + j], acc[j]);
                acc[j] = fmaf(hv.z, W2[(4 * k4 + 2) * O + j], acc[j]);
                acc[j] = fmaf(hv.w, W2[(4 * k4 + 3) * O + j], acc[j]);
            }
        }
        float d = dinv[n];
#pragma unroll
        for (int j = 0; j < O; ++j) zbuf[t * O + j] = acc[j] * d;
    }
    __syncthreads();
    int total = (min(n0 + 256, n_nodes) - n0) * O;
    float* zo = zs + (size_t)n0 * O;
    for (int i = t; i < total; i += 256) zo[i] = zbuf[i];
}

// out[n][j] = dinv[n] * (zs[n][j] + sum_{k in row} zs[esrc[k]][j]) + b2[j]
__global__ __launch_bounds__(256) void k_gather2(
    const float* __restrict__ zs, const int* __restrict__ rowptr,
    const int* __restrict__ esrc, const float* __restrict__ dinv,
    const float* __restrict__ b2, float* __restrict__ out, int n_nodes) {
    const int j = threadIdx.x & 15;
    const int n = blockIdx.x * 16 + (threadIdx.x >> 4);
    if (n >= n_nodes || j >= O) return;
    int beg = rowptr[n], end = rowptr[n + 1];
    float acc = zs[(size_t)n * O + j];
    int k = beg;
    for (; k + 1 < end; k += 2) {
        int s0 = esrc[k], s1 = esrc[k + 1];
        acc += zs[(size_t)s0 * O + j] + zs[(size_t)s1 * O + j];
    }
    for (; k < end; ++k) acc += zs[(size_t)esrc[k] * O + j];
    out[(size_t)n * O + j] = fmaf(dinv[n], acc, b2[j]);
}

extern "C" void kernel_launch(void* const* d_in, const int* in_sizes, int n_in,
                              void* d_out, int out_size, void* d_ws, size_t ws_size,
                              hipStream_t stream) {
    const float* x  = (const float*)d_in[0];
    const int*   ei = (const int*)d_in[1];
    const float* W1 = (const float*)d_in[2];
    const float* b1 = (const float*)d_in[3];
    const float* W2 = (const float*)d_in[4];
    const float* b2 = (const float*)d_in[5];
    float* out = (float*)d_out;

    const int N = in_sizes[0] / F;   // 100000
    const int E = in_sizes[1] / 2;   // 1600000
    const int* src = ei;
    const int* dst = ei + E;

    // Workspace: y[N*H] | h[N*H] (front aliased by ebuf 19.3MB; tail 32KB holds W1t)
    //          | zs[N*O] | dinv[N] | cnt[N+1] | rowptr[N+1] | bsum[512]
    //          | bcntg[256] | esrc[E]
    float* y    = (float*)d_ws;
    float* h    = y + (size_t)N * H;
    uint2* ebuf = (uint2*)h;                       // consumed before h is written
    float* W1t  = h + (size_t)N * H - F * H;       // tail of h region, after ebuf
    float* zs   = h + (size_t)N * H;
    float* dinv = zs + (size_t)N * O;
    int* cnt    = (int*)(dinv + N);
    int* rowptr = cnt + (N + 1);
    int* bsum   = rowptr + (N + 1);
    int* bcntg  = bsum + 512;
    int* esrc   = bcntg + 256;

    const int NBUK   = (N + 511) >> 9;          // 196
    const int nb_n1  = (N + 256) / 256;         // covers N+1 entries (391 <= 512)
    const int nb_bin = (E + EPB - 1) / EPB;     // 391

    k_zero_misc<<<1, 256, 0, stream>>>(bcntg, cnt, N);
    k_wt<<<(F * H + 255) / 256, 256, 0, stream>>>(W1, W1t);
    k_bin<<<nb_bin, 256, 0, stream>>>(src, dst, bcntg, ebuf, E);
    k_bcount<<<NBUK, 256, 0, stream>>>(ebuf, bcntg, cnt, dinv, N);
    k_scan1<<<nb_n1, 256, 0, stream>>>(cnt, rowptr, bsum, N + 1);
    k_scan2<<<1, 512, 0, stream>>>(bsum, nb_n1);
    k_scan3<<<nb_n1, 256, 0, stream>>>(rowptr, bsum, N + 1);
    k_fillb<<<NBUK, 256, 0, stream>>>(ebuf, bcntg, rowptr, esrc, N);
    k_gemm1<<<(N + 63) / 64, 256, 0, stream>>>(x, W1t, dinv, y, N);
    k_gather1<<<(N + 3) / 4, 256, 0, stream>>>(y, rowptr, esrc, dinv, b1, h, N);
    k_zs<<<(N + 3) / 4, 256, 0, stream>>>(h, W2, dinv, zs, N);
    k_gather2<<<(N + 15) / 16, 256, 0, stream>>>(zs, rowptr, esrc, dinv, b2, out, N);
}

// Round 6
// 277.907 us; speedup vs baseline: 2.3794x; 1.0605x over previous
//
#include <hip/hip_runtime.h>
#include <hip/hip_fp16.h>

// GCN 2-layer forward on gfx950 — CSR-gather with fp16-compressed intermediates
// (fp32 accumulation), bucketed counting-sort CSR build, LDS-tiled fp32 GEMM.
// F=128 in, H=64 hidden, O=10 out. N=100000 nodes, E=1600000 edges.
static constexpr int F = 128;
static constexpr int H = 64;
static constexpr int O = 10;
static constexpr int NBUK_MAX = 256;   // buckets of 512 nodes (dst>>9); N=100k -> 196 used
static constexpr int CAP = 12288;      // per-bucket edge capacity (avg ~8192)
static constexpr int EPB = 4096;       // edges per block in k_bin
static constexpr int TS = 132;         // bt LDS stride (128 + 4 pad)
static constexpr int XS = 68;          // xs LDS stride (64 + 4 pad)

__global__ __launch_bounds__(256) void k_zero_misc(int* __restrict__ bcntg,
                                                   int* __restrict__ cnt, int n) {
    int t = threadIdx.x;
    bcntg[t] = 0;            // 256 entries
    if (t == 0) cnt[n] = 0;  // scan pad entry
}

// Bin edges by bucket = dst>>9. Per-block LDS histogram -> one global atomic
// reservation per (block,bucket) -> bucket-contiguous (src,dst) 8B writes.
__global__ __launch_bounds__(256) void k_bin(const int* __restrict__ src,
                                             const int* __restrict__ dst,
                                             int* __restrict__ bcntg,
                                             uint2* __restrict__ ebuf, int e_total) {
    __shared__ int hist[NBUK_MAX];
    __shared__ int base[NBUK_MAX];
    __shared__ int loc[NBUK_MAX];
    int t = threadIdx.x;
    hist[t] = 0;
    loc[t] = 0;
    __syncthreads();
    int i0 = blockIdx.x * EPB;
    int i1 = min(i0 + EPB, e_total);
    for (int i = i0 + t; i < i1; i += 256) atomicAdd(&hist[dst[i] >> 9], 1);
    __syncthreads();
    if (hist[t] > 0) base[t] = atomicAdd(&bcntg[t], hist[t]);
    __syncthreads();
    for (int i = i0 + t; i < i1; i += 256) {
        int d = dst[i];
        int b = d >> 9;
        int r = base[b] + atomicAdd(&loc[b], 1);
        if (r < CAP) ebuf[(size_t)b * CAP + r] = make_uint2((unsigned)src[i], (unsigned)d);
    }
}

// Per-bucket in-degree count (LDS counters) + dinv. One block per bucket.
__global__ __launch_bounds__(256) void k_bcount(const uint2* __restrict__ ebuf,
                                                const int* __restrict__ bcntg,
                                                int* __restrict__ cnt,
                                                float* __restrict__ dinv, int n_nodes) {
    __shared__ int hc[512];
    int t = threadIdx.x, b = blockIdx.x, n0 = b << 9;
    hc[t] = 0;
    hc[t + 256] = 0;
    __syncthreads();
    int cb = bcntg[b];
    const uint2* eb = ebuf + (size_t)b * CAP;
    for (int i = t; i < cb; i += 256) atomicAdd(&hc[eb[i].y - n0], 1);
    __syncthreads();
#pragma unroll
    for (int u = 0; u < 2; ++u) {
        int n = n0 + t + u * 256;
        if (n < n_nodes) {
            int c = hc[t + u * 256];
            cnt[n] = c;
            dinv[n] = rsqrtf((float)c + 1.0f);   // +1 self-loop
        }
    }
}

// Exclusive scan of cnt[0..n) (n = N+1 entries) -> rowptr, per-256 block + bsum.
__global__ __launch_bounds__(256) void k_scan1(const int* __restrict__ cnt,
                                               int* __restrict__ rowptr,
                                               int* __restrict__ bsum, int n) {
    __shared__ int s[256];
    int t = threadIdx.x;
    int i = blockIdx.x * 256 + t;
    int v = (i < n) ? cnt[i] : 0;
    s[t] = v;
    __syncthreads();
    for (int off = 1; off < 256; off <<= 1) {
        int x = (t >= off) ? s[t - off] : 0;
        __syncthreads();
        s[t] += x;
        __syncthreads();
    }
    if (i < n) rowptr[i] = s[t] - v;
    if (t == 255) bsum[blockIdx.x] = s[255];
}

__global__ __launch_bounds__(512) void k_scan2(int* __restrict__ bsum, int nb) {
    __shared__ int s[512];
    int t = threadIdx.x;
    int v = (t < nb) ? bsum[t] : 0;
    s[t] = v;
    __syncthreads();
    for (int off = 1; off < 512; off <<= 1) {
        int x = (t >= off) ? s[t - off] : 0;
        __syncthreads();
        s[t] += x;
        __syncthreads();
    }
    if (t < nb) bsum[t] = s[t] - v;
}

__global__ __launch_bounds__(256) void k_scan3(int* __restrict__ rowptr,
                                               const int* __restrict__ bsum, int n) {
    int i = blockIdx.x * 256 + threadIdx.x;
    if (i < n) rowptr[i] += bsum[blockIdx.x];
}

// Per-bucket CSR fill: LDS cursors, esrc writes confined to one ~34KB window per CU.
__global__ __launch_bounds__(256) void k_fillb(const uint2* __restrict__ ebuf,
                                               const int* __restrict__ bcntg,
                                               const int* __restrict__ rowptr,
                                               int* __restrict__ esrc, int n_nodes) {
    __shared__ int curs[512];
    int t = threadIdx.x, b = blockIdx.x, n0 = b << 9;
#pragma unroll
    for (int u = 0; u < 2; ++u) {
        int n = n0 + t + u * 256;
        if (n < n_nodes) curs[t + u * 256] = rowptr[n];
    }
    __syncthreads();
    int cb = bcntg[b];
    const uint2* eb = ebuf + (size_t)b * CAP;
    for (int i = t; i < cb; i += 256) {
        uint2 e = eb[i];
        int r = atomicAdd(&curs[e.y - n0], 1);
        esrc[r] = (int)e.x;
    }
}

// W1t[c][k] = W1[k][c]  (one-time 32KB transpose so gemm1 staging is a pure copy)
__global__ __launch_bounds__(256) void k_wt(const float* __restrict__ W1,
                                            float* __restrict__ W1t) {
    int t = blockIdx.x * 256 + threadIdx.x;
    if (t < F * H) {
        int k = t >> 6, c = t & 63;
        W1t[c * F + k] = W1[k * H + c];
    }
}

// y = fp16((x @ W1) * dinv[n]), LDS-tiled: 64-row tiles, W1^T resident in LDS,
// per-thread 4x4 register tile (rows/cols strided by 16 -> <=2-way LDS aliasing).
__global__ __launch_bounds__(256) void k_gemm1(
    const float* __restrict__ x, const float* __restrict__ W1t,
    const float* __restrict__ dinv, __half* __restrict__ y, int n_nodes) {
    __shared__ float bt[H * TS];   // [col][k], 33792 B
    __shared__ float xs[64 * XS];  // [row][k-half], 17408 B
    const int tid = threadIdx.x;
    const int rg = tid >> 4;       // 0..15
    const int cg = tid & 15;       // 0..15
    const int row0 = blockIdx.x * 64;

    for (int i = tid; i < H * (F / 4); i += 256) {
        int c = i >> 5, k4 = i & 31;
        float4 v = *(const float4*)&W1t[c * F + 4 * k4];
        *(float4*)&bt[c * TS + 4 * k4] = v;
    }

    float acc[4][4];
#pragma unroll
    for (int i = 0; i < 4; ++i)
#pragma unroll
        for (int j = 0; j < 4; ++j) acc[i][j] = 0.f;

    for (int kh = 0; kh < 2; ++kh) {
        __syncthreads();
        for (int i = tid; i < 64 * 16; i += 256) {
            int r = i >> 4, k4 = i & 15;
            int gr = row0 + r;
            float4 v = (gr < n_nodes)
                           ? *(const float4*)&x[(size_t)gr * F + kh * 64 + 4 * k4]
                           : make_float4(0.f, 0.f, 0.f, 0.f);
            *(float4*)&xs[r * XS + 4 * k4] = v;
        }
        __syncthreads();
#pragma unroll
        for (int k4 = 0; k4 < 16; ++k4) {
            float4 a[4], b[4];
#pragma unroll
            for (int c = 0; c < 4; ++c)
                a[c] = *(const float4*)&xs[(rg + 16 * c) * XS + 4 * k4];
#pragma unroll
            for (int c = 0; c < 4; ++c)
                b[c] = *(const float4*)&bt[(cg + 16 * c) * TS + kh * 64 + 4 * k4];
#pragma unroll
            for (int i = 0; i < 4; ++i)
#pragma unroll
                for (int j = 0; j < 4; ++j) {
                    acc[i][j] = fmaf(a[i].x, b[j].x, acc[i][j]);
                    acc[i][j] = fmaf(a[i].y, b[j].y, acc[i][j]);
                    acc[i][j] = fmaf(a[i].z, b[j].z, acc[i][j]);
                    acc[i][j] = fmaf(a[i].w, b[j].w, acc[i][j]);
                }
        }
    }
#pragma unroll
    for (int i = 0; i < 4; ++i) {
        int r = row0 + rg + 16 * i;
        if (r < n_nodes) {
            float d = dinv[r];
#pragma unroll
            for (int j = 0; j < 4; ++j)
                y[(size_t)r * H + cg + 16 * j] = __float2half(acc[i][j] * d);
        }
    }
}

// h[n][j] = fp16(relu(dinv[n]*(y[n][j] + sum_k y[esrc[k]][j]) + b1[j]))
// Wave per node, lane = feature; 8-deep unroll for memory-level parallelism.
__global__ __launch_bounds__(256) void k_gather1(
    const __half* __restrict__ y, const int* __restrict__ rowptr,
    const int* __restrict__ esrc, const float* __restrict__ dinv,
    const float* __restrict__ b1, __half* __restrict__ h, int n_nodes) {
    const int j = threadIdx.x & 63;
    const int n = blockIdx.x * 4 + (threadIdx.x >> 6);
    if (n >= n_nodes) return;
    int beg = rowptr[n], end = rowptr[n + 1];
    float acc = __half2float(y[(size_t)n * H + j]);
    int k = beg;
    for (; k + 7 < end; k += 8) {
        int s0 = esrc[k], s1 = esrc[k + 1], s2 = esrc[k + 2], s3 = esrc[k + 3];
        int s4 = esrc[k + 4], s5 = esrc[k + 5], s6 = esrc[k + 6], s7 = esrc[k + 7];
        float v0 = __half2float(y[(size_t)s0 * H + j]);
        float v1 = __half2float(y[(size_t)s1 * H + j]);
        float v2 = __half2float(y[(size_t)s2 * H + j]);
        float v3 = __half2float(y[(size_t)s3 * H + j]);
        float v4 = __half2float(y[(size_t)s4 * H + j]);
        float v5 = __half2float(y[(size_t)s5 * H + j]);
        float v6 = __half2float(y[(size_t)s6 * H + j]);
        float v7 = __half2float(y[(size_t)s7 * H + j]);
        acc += ((v0 + v1) + (v2 + v3)) + ((v4 + v5) + (v6 + v7));
    }
    for (; k < end; ++k) acc += __half2float(y[(size_t)esrc[k] * H + j]);
    h[(size_t)n * H + j] = __float2half(fmaxf(fmaf(dinv[n], acc, b1[j]), 0.0f));
}

// zs[n][j] = fp16(dinv[n] * (h[n] @ W2)[j]).  Thread per node: h row via __half2,
// W2 at compile-time-constant offsets -> wave-uniform s_load (SMEM pipe),
// results staged in LDS for fully-coalesced output writes.
__global__ __launch_bounds__(256) void k_zs(
    const __half* __restrict__ h, const float* __restrict__ W2,
    const float* __restrict__ dinv, __half* __restrict__ zs, int n_nodes) {
    __shared__ __half zbuf[256 * O];     // 5 KB
    const int t = threadIdx.x;
    const int n0 = blockIdx.x * 256;
    const int n = n0 + t;
    if (n < n_nodes) {
        float acc[O];
#pragma unroll
        for (int j = 0; j < O; ++j) acc[j] = 0.f;
        const __half2* hr = (const __half2*)(h + (size_t)n * H);
#pragma unroll
        for (int k2 = 0; k2 < H / 2; ++k2) {
            float2 hv = __half22float2(hr[k2]);
#pragma unroll
            for (int j = 0; j < O; ++j) {
                acc[j] = fmaf(hv.x, W2[(2 * k2 + 0) * O + j], acc[j]);
                acc[j] = fmaf(hv.y, W2[(2 * k2 + 1) * O + j], acc[j]);
            }
        }
        float d = dinv[n];
#pragma unroll
        for (int j = 0; j < O; ++j) zbuf[t * O + j] = __float2half(acc[j] * d);
    }
    __syncthreads();
    int total = (min(n0 + 256, n_nodes) - n0) * O;   // halves; always even
    unsigned* zo = (unsigned*)(zs + (size_t)n0 * O); // n0*O*2 bytes, 4B-aligned
    const unsigned* zb = (const unsigned*)zbuf;
    for (int i = t; i < total / 2; i += 256) zo[i] = zb[i];
}

// out[n][j] = dinv[n] * (zs[n][j] + sum_k zs[esrc[k]][j]) + b2[j]   (fp32 out)
__global__ __launch_bounds__(256) void k_gather2(
    const __half* __restrict__ zs, const int* __restrict__ rowptr,
    const int* __restrict__ esrc, const float* __restrict__ dinv,
    const float* __restrict__ b2, float* __restrict__ out, int n_nodes) {
    const int j = threadIdx.x & 15;
    const int n = blockIdx.x * 16 + (threadIdx.x >> 4);
    if (n >= n_nodes || j >= O) return;
    int beg = rowptr[n], end = rowptr[n + 1];
    float acc = __half2float(zs[(size_t)n * O + j]);
    int k = beg;
    for (; k + 3 < end; k += 4) {
        int s0 = esrc[k], s1 = esrc[k + 1], s2 = esrc[k + 2], s3 = esrc[k + 3];
        float v0 = __half2float(zs[(size_t)s0 * O + j]);
        float v1 = __half2float(zs[(size_t)s1 * O + j]);
        float v2 = __half2float(zs[(size_t)s2 * O + j]);
        float v3 = __half2float(zs[(size_t)s3 * O + j]);
        acc += (v0 + v1) + (v2 + v3);
    }
    for (; k < end; ++k) acc += __half2float(zs[(size_t)esrc[k] * O + j]);
    out[(size_t)n * O + j] = fmaf(dinv[n], acc, b2[j]);
}

extern "C" void kernel_launch(void* const* d_in, const int* in_sizes, int n_in,
                              void* d_out, int out_size, void* d_ws, size_t ws_size,
                              hipStream_t stream) {
    const float* x  = (const float*)d_in[0];
    const int*   ei = (const int*)d_in[1];
    const float* W1 = (const float*)d_in[2];
    const float* b1 = (const float*)d_in[3];
    const float* W2 = (const float*)d_in[4];
    const float* b2 = (const float*)d_in[5];
    float* out = (float*)d_out;

    const int N = in_sizes[0] / F;   // 100000
    const int E = in_sizes[1] / 2;   // 1600000
    const int* src = ei;
    const int* dst = ei + E;

    // Workspace (region sizes kept in fp32 units; fp16 arrays use the front half
    // of their region): y[N*H] | h-region[N*H] (front aliased by ebuf 19.3MB,
    // consumed before h written; tail 32KB = W1t) | zs[N*O] | dinv[N] | cnt[N+1]
    // | rowptr[N+1] | bsum[512] | bcntg[256] | esrc[E]
    float* yr   = (float*)d_ws;
    float* hr   = yr + (size_t)N * H;
    __half* y   = (__half*)yr;
    __half* h   = (__half*)hr;
    uint2* ebuf = (uint2*)hr;                      // consumed before h is written
    float* W1t  = hr + (size_t)N * H - F * H;      // tail of h region, after ebuf
    float* zr   = hr + (size_t)N * H;
    __half* zs  = (__half*)zr;
    float* dinv = zr + (size_t)N * O;
    int* cnt    = (int*)(dinv + N);
    int* rowptr = cnt + (N + 1);
    int* bsum   = rowptr + (N + 1);
    int* bcntg  = bsum + 512;
    int* esrc   = bcntg + 256;

    const int NBUK   = (N + 511) >> 9;          // 196
    const int nb_n1  = (N + 256) / 256;         // covers N+1 entries (391 <= 512)
    const int nb_bin = (E + EPB - 1) / EPB;     // 391

    k_zero_misc<<<1, 256, 0, stream>>>(bcntg, cnt, N);
    k_wt<<<(F * H + 255) / 256, 256, 0, stream>>>(W1, W1t);
    k_bin<<<nb_bin, 256, 0, stream>>>(src, dst, bcntg, ebuf, E);
    k_bcount<<<NBUK, 256, 0, stream>>>(ebuf, bcntg, cnt, dinv, N);
    k_scan1<<<nb_n1, 256, 0, stream>>>(cnt, rowptr, bsum, N + 1);
    k_scan2<<<1, 512, 0, stream>>>(bsum, nb_n1);
    k_scan3<<<nb_n1, 256, 0, stream>>>(rowptr, bsum, N + 1);
    k_fillb<<<NBUK, 256, 0, stream>>>(ebuf, bcntg, rowptr, esrc, N);
    k_gemm1<<<(N + 63) / 64, 256, 0, stream>>>(x, W1t, dinv, y, N);
    k_gather1<<<(N + 3) / 4, 256, 0, stream>>>(y, rowptr, esrc, dinv, b1, h, N);
    k_zs<<<(N + 255) / 256, 256, 0, stream>>>(h, W2, dinv, zs, N);
    k_gather2<<<(N + 15) / 16, 256, 0, stream>>>(zs, rowptr, esrc, dinv, b2, out, N);
}

// Round 7
// 262.882 us; speedup vs baseline: 2.5154x; 1.0572x over previous
//
#include <hip/hip_runtime.h>
#include <hip/hip_fp16.h>

// GCN 2-layer forward on gfx950 — CSR-gather with fp16-compressed intermediates
// (fp32 accumulation), bucketed counting-sort CSR build, LDS-tiled fp32 GEMM.
// F=128 in, H=64 hidden, O=10 out. N=100000 nodes, E=1600000 edges.
static constexpr int F = 128;
static constexpr int H = 64;
static constexpr int O = 10;
static constexpr int NBUK_MAX = 256;   // buckets of 512 nodes (dst>>9); N=100k -> 196 used
static constexpr int CAP = 12288;      // per-bucket edge capacity (avg ~8192)
static constexpr int EPB = 4096;       // edges per block in k_bin
static constexpr int TS = 132;         // bt LDS stride (128 + 4 pad)
static constexpr int XS = 68;          // xs LDS stride (64 + 4 pad)

// block 0: zero bcntg + scan pad; blocks 1..32: transpose W1 -> W1t (32KB).
__global__ __launch_bounds__(256) void k_init(int* __restrict__ bcntg,
                                              int* __restrict__ cnt, int n,
                                              const float* __restrict__ W1,
                                              float* __restrict__ W1t) {
    int b = blockIdx.x, t = threadIdx.x;
    if (b == 0) {
        bcntg[t] = 0;
        if (t == 0) cnt[n] = 0;
    } else {
        int i = (b - 1) * 256 + t;   // i < F*H = 8192
        int k = i >> 6, c = i & 63;
        W1t[c * F + k] = W1[k * H + c];
    }
}

// Bin edges by bucket = dst>>9. Per-block LDS histogram -> one global atomic
// reservation per (block,bucket) -> bucket-contiguous (src,dst) 8B writes.
__global__ __launch_bounds__(256) void k_bin(const int* __restrict__ src,
                                             const int* __restrict__ dst,
                                             int* __restrict__ bcntg,
                                             uint2* __restrict__ ebuf, int e_total) {
    __shared__ int hist[NBUK_MAX];
    __shared__ int base[NBUK_MAX];
    __shared__ int loc[NBUK_MAX];
    int t = threadIdx.x;
    hist[t] = 0;
    loc[t] = 0;
    __syncthreads();
    int i0 = blockIdx.x * EPB;
    int i1 = min(i0 + EPB, e_total);
    for (int i = i0 + t; i < i1; i += 256) atomicAdd(&hist[dst[i] >> 9], 1);
    __syncthreads();
    if (hist[t] > 0) base[t] = atomicAdd(&bcntg[t], hist[t]);
    __syncthreads();
    for (int i = i0 + t; i < i1; i += 256) {
        int d = dst[i];
        int b = d >> 9;
        int r = base[b] + atomicAdd(&loc[b], 1);
        if (r < CAP) ebuf[(size_t)b * CAP + r] = make_uint2((unsigned)src[i], (unsigned)d);
    }
}

// Per-bucket in-degree count (LDS counters) + dinv. One block per bucket.
__global__ __launch_bounds__(256) void k_bcount(const uint2* __restrict__ ebuf,
                                                const int* __restrict__ bcntg,
                                                int* __restrict__ cnt,
                                                float* __restrict__ dinv, int n_nodes) {
    __shared__ int hc[512];
    int t = threadIdx.x, b = blockIdx.x, n0 = b << 9;
    hc[t] = 0;
    hc[t + 256] = 0;
    __syncthreads();
    int cb = bcntg[b];
    const uint2* eb = ebuf + (size_t)b * CAP;
    for (int i = t; i < cb; i += 256) atomicAdd(&hc[eb[i].y - n0], 1);
    __syncthreads();
#pragma unroll
    for (int u = 0; u < 2; ++u) {
        int n = n0 + t + u * 256;
        if (n < n_nodes) {
            int c = hc[t + u * 256];
            cnt[n] = c;
            dinv[n] = rsqrtf((float)c + 1.0f);   // +1 self-loop
        }
    }
}

// Exclusive scan of cnt[0..n) (n = N+1 entries) -> rowptr, per-256 block + bsum.
__global__ __launch_bounds__(256) void k_scan1(const int* __restrict__ cnt,
                                               int* __restrict__ rowptr,
                                               int* __restrict__ bsum, int n) {
    __shared__ int s[256];
    int t = threadIdx.x;
    int i = blockIdx.x * 256 + t;
    int v = (i < n) ? cnt[i] : 0;
    s[t] = v;
    __syncthreads();
    for (int off = 1; off < 256; off <<= 1) {
        int x = (t >= off) ? s[t - off] : 0;
        __syncthreads();
        s[t] += x;
        __syncthreads();
    }
    if (i < n) rowptr[i] = s[t] - v;
    if (t == 255) bsum[blockIdx.x] = s[255];
}

__global__ __launch_bounds__(512) void k_scan2(int* __restrict__ bsum, int nb) {
    __shared__ int s[512];
    int t = threadIdx.x;
    int v = (t < nb) ? bsum[t] : 0;
    s[t] = v;
    __syncthreads();
    for (int off = 1; off < 512; off <<= 1) {
        int x = (t >= off) ? s[t - off] : 0;
        __syncthreads();
        s[t] += x;
        __syncthreads();
    }
    if (t < nb) bsum[t] = s[t] - v;
}

__global__ __launch_bounds__(256) void k_scan3(int* __restrict__ rowptr,
                                               const int* __restrict__ bsum, int n) {
    int i = blockIdx.x * 256 + threadIdx.x;
    if (i < n) rowptr[i] += bsum[blockIdx.x];
}

// Per-bucket CSR fill: LDS cursors, esrc writes confined to one ~34KB window per CU.
__global__ __launch_bounds__(256) void k_fillb(const uint2* __restrict__ ebuf,
                                               const int* __restrict__ bcntg,
                                               const int* __restrict__ rowptr,
                                               int* __restrict__ esrc, int n_nodes) {
    __shared__ int curs[512];
    int t = threadIdx.x, b = blockIdx.x, n0 = b << 9;
#pragma unroll
    for (int u = 0; u < 2; ++u) {
        int n = n0 + t + u * 256;
        if (n < n_nodes) curs[t + u * 256] = rowptr[n];
    }
    __syncthreads();
    int cb = bcntg[b];
    const uint2* eb = ebuf + (size_t)b * CAP;
    for (int i = t; i < cb; i += 256) {
        uint2 e = eb[i];
        int r = atomicAdd(&curs[e.y - n0], 1);
        esrc[r] = (int)e.x;
    }
}

// y = fp16((x @ W1) * dinv[n]), LDS-tiled: 64-row tiles, W1^T resident in LDS,
// per-thread 4x4 register tile (rows/cols strided by 16 -> <=2-way LDS aliasing).
__global__ __launch_bounds__(256) void k_gemm1(
    const float* __restrict__ x, const float* __restrict__ W1t,
    const float* __restrict__ dinv, __half* __restrict__ y, int n_nodes) {
    __shared__ float bt[H * TS];   // [col][k], 33792 B
    __shared__ float xs[64 * XS];  // [row][k-half], 17408 B
    const int tid = threadIdx.x;
    const int rg = tid >> 4;       // 0..15
    const int cg = tid & 15;       // 0..15
    const int row0 = blockIdx.x * 64;

    for (int i = tid; i < H * (F / 4); i += 256) {
        int c = i >> 5, k4 = i & 31;
        float4 v = *(const float4*)&W1t[c * F + 4 * k4];
        *(float4*)&bt[c * TS + 4 * k4] = v;
    }

    float acc[4][4];
#pragma unroll
    for (int i = 0; i < 4; ++i)
#pragma unroll
        for (int j = 0; j < 4; ++j) acc[i][j] = 0.f;

    for (int kh = 0; kh < 2; ++kh) {
        __syncthreads();
        for (int i = tid; i < 64 * 16; i += 256) {
            int r = i >> 4, k4 = i & 15;
            int gr = row0 + r;
            float4 v = (gr < n_nodes)
                           ? *(const float4*)&x[(size_t)gr * F + kh * 64 + 4 * k4]
                           : make_float4(0.f, 0.f, 0.f, 0.f);
            *(float4*)&xs[r * XS + 4 * k4] = v;
        }
        __syncthreads();
#pragma unroll
        for (int k4 = 0; k4 < 16; ++k4) {
            float4 a[4], b[4];
#pragma unroll
            for (int c = 0; c < 4; ++c)
                a[c] = *(const float4*)&xs[(rg + 16 * c) * XS + 4 * k4];
#pragma unroll
            for (int c = 0; c < 4; ++c)
                b[c] = *(const float4*)&bt[(cg + 16 * c) * TS + kh * 64 + 4 * k4];
#pragma unroll
            for (int i = 0; i < 4; ++i)
#pragma unroll
                for (int j = 0; j < 4; ++j) {
                    acc[i][j] = fmaf(a[i].x, b[j].x, acc[i][j]);
                    acc[i][j] = fmaf(a[i].y, b[j].y, acc[i][j]);
                    acc[i][j] = fmaf(a[i].z, b[j].z, acc[i][j]);
                    acc[i][j] = fmaf(a[i].w, b[j].w, acc[i][j]);
                }
        }
    }
#pragma unroll
    for (int i = 0; i < 4; ++i) {
        int r = row0 + rg + 16 * i;
        if (r < n_nodes) {
            float d = dinv[r];
#pragma unroll
            for (int j = 0; j < 4; ++j)
                y[(size_t)r * H + cg + 16 * j] = __float2half(acc[i][j] * d);
        }
    }
}

// h[n] = fp16(relu(dinv[n]*(y[n] + sum_k y[esrc[k]]) + b1))
// Wave per node. Lane = (group g in {0,1}, feature-pair c in [0,32)): each
// __half2 load covers 2 features x 2 edges/wave-instruction. Edge indices are
// preloaded coalesced into one register (deg<=64 fast path) and fetched per
// step via shfl — no dependent esrc loads in the gather chain. 16 edges in
// flight per wave (unroll 8 x 2 groups).
__global__ __launch_bounds__(256) void k_gather1(
    const __half2* __restrict__ y2, const int* __restrict__ rowptr,
    const int* __restrict__ esrc, const float* __restrict__ dinv,
    const float* __restrict__ b1, __half2* __restrict__ h2, int n_nodes) {
    const int l = threadIdx.x & 63;
    const int g = l >> 5;          // edge-slot parity
    const int c = l & 31;          // feature-pair index
    const int n = blockIdx.x * 4 + (threadIdx.x >> 6);
    if (n >= n_nodes) return;
    const int beg = rowptr[n], end = rowptr[n + 1];
    const int deg = end - beg;
    int idx = (l < deg) ? esrc[beg + l] : 0;   // one coalesced preload
    float2 acc = make_float2(0.f, 0.f);
    if (g == 0) {                              // self-loop in group 0 only
        float2 v = __half22float2(y2[(size_t)n * 32 + c]);
        acc.x += v.x;
        acc.y += v.y;
    }
    const int dlim = min(deg, 64);
    int k = 0;
    for (; k + 15 < dlim; k += 16) {
#pragma unroll
        for (int u = 0; u < 8; ++u) {
            int s = __shfl(idx, k + 2 * u + g, 64);
            float2 v = __half22float2(y2[(size_t)s * 32 + c]);
            acc.x += v.x;
            acc.y += v.y;
        }
    }
    for (; k < dlim; k += 2) {
        int slot = k + g;
        int s = __shfl(idx, min(slot, dlim - 1), 64);
        if (slot < dlim) {
            float2 v = __half22float2(y2[(size_t)s * 32 + c]);
            acc.x += v.x;
            acc.y += v.y;
        }
    }
    for (int kk = 64 + g; kk < deg; kk += 2) {  // rare deg>64 fallback
        int s = esrc[beg + kk];
        float2 v = __half22float2(y2[(size_t)s * 32 + c]);
        acc.x += v.x;
        acc.y += v.y;
    }
    acc.x += __shfl_xor(acc.x, 32, 64);         // fold the two edge groups
    acc.y += __shfl_xor(acc.y, 32, 64);
    if (g == 0) {
        float2 bb = ((const float2*)b1)[c];
        float d = dinv[n];
        float hx = fmaxf(fmaf(d, acc.x, bb.x), 0.0f);
        float hy = fmaxf(fmaf(d, acc.y, bb.y), 0.0f);
        h2[(size_t)n * 32 + c] = __floats2half2_rn(hx, hy);
    }
}

// zs[n][j] = fp16(dinv[n] * (h[n] @ W2)[j]).  Thread per node: h row via __half2,
// W2 at compile-time-constant offsets -> wave-uniform s_load (SMEM pipe),
// results staged in LDS for fully-coalesced output writes.
__global__ __launch_bounds__(256) void k_zs(
    const __half* __restrict__ h, const float* __restrict__ W2,
    const float* __restrict__ dinv, __half* __restrict__ zs, int n_nodes) {
    __shared__ __half zbuf[256 * O];     // 5 KB
    const int t = threadIdx.x;
    const int n0 = blockIdx.x * 256;
    const int n = n0 + t;
    if (n < n_nodes) {
        float acc[O];
#pragma unroll
        for (int j = 0; j < O; ++j) acc[j] = 0.f;
        const __half2* hr = (const __half2*)(h + (size_t)n * H);
#pragma unroll
        for (int k2 = 0; k2 < H / 2; ++k2) {
            float2 hv = __half22float2(hr[k2]);
#pragma unroll
            for (int j = 0; j < O; ++j) {
                acc[j] = fmaf(hv.x, W2[(2 * k2 + 0) * O + j], acc[j]);
                acc[j] = fmaf(hv.y, W2[(2 * k2 + 1) * O + j], acc[j]);
            }
        }
        float d = dinv[n];
#pragma unroll
        for (int j = 0; j < O; ++j) zbuf[t * O + j] = __float2half(acc[j] * d);
    }
    __syncthreads();
    int total = (min(n0 + 256, n_nodes) - n0) * O;   // halves; always even
    unsigned* zo = (unsigned*)(zs + (size_t)n0 * O); // n0*O*2 bytes, 4B-aligned
    const unsigned* zb = (const unsigned*)zbuf;
    for (int i = t; i < total / 2; i += 256) zo[i] = zb[i];
}

// out[n][j] = dinv[n] * (zs[n][j] + sum_k zs[esrc[k]][j]) + b2[j]   (fp32 out)
__global__ __launch_bounds__(256) void k_gather2(
    const __half* __restrict__ zs, const int* __restrict__ rowptr,
    const int* __restrict__ esrc, const float* __restrict__ dinv,
    const float* __restrict__ b2, float* __restrict__ out, int n_nodes) {
    const int j = threadIdx.x & 15;
    const int n = blockIdx.x * 16 + (threadIdx.x >> 4);
    if (n >= n_nodes || j >= O) return;
    int beg = rowptr[n], end = rowptr[n + 1];
    float acc = __half2float(zs[(size_t)n * O + j]);
    int k = beg;
    for (; k + 3 < end; k += 4) {
        int s0 = esrc[k], s1 = esrc[k + 1], s2 = esrc[k + 2], s3 = esrc[k + 3];
        float v0 = __half2float(zs[(size_t)s0 * O + j]);
        float v1 = __half2float(zs[(size_t)s1 * O + j]);
        float v2 = __half2float(zs[(size_t)s2 * O + j]);
        float v3 = __half2float(zs[(size_t)s3 * O + j]);
        acc += (v0 + v1) + (v2 + v3);
    }
    for (; k < end; ++k) acc += __half2float(zs[(size_t)esrc[k] * O + j]);
    out[(size_t)n * O + j] = fmaf(dinv[n], acc, b2[j]);
}

extern "C" void kernel_launch(void* const* d_in, const int* in_sizes, int n_in,
                              void* d_out, int out_size, void* d_ws, size_t ws_size,
                              hipStream_t stream) {
    const float* x  = (const float*)d_in[0];
    const int*   ei = (const int*)d_in[1];
    const float* W1 = (const float*)d_in[2];
    const float* b1 = (const float*)d_in[3];
    const float* W2 = (const float*)d_in[4];
    const float* b2 = (const float*)d_in[5];
    float* out = (float*)d_out;

    const int N = in_sizes[0] / F;   // 100000
    const int E = in_sizes[1] / 2;   // 1600000
    const int* src = ei;
    const int* dst = ei + E;

    // Workspace (region sizes kept in fp32 units; fp16 arrays use the front half
    // of their region): y[N*H] | h-region[N*H] (front aliased by ebuf 19.3MB,
    // consumed before h written; tail 32KB = W1t) | zs[N*O] | dinv[N] | cnt[N+1]
    // | rowptr[N+1] | bsum[512] | bcntg[256] | esrc[E]
    float* yr   = (float*)d_ws;
    float* hr   = yr + (size_t)N * H;
    __half* y   = (__half*)yr;
    __half* h   = (__half*)hr;
    uint2* ebuf = (uint2*)hr;                      // consumed before h is written
    float* W1t  = hr + (size_t)N * H - F * H;      // tail of h region, after ebuf
    float* zr   = hr + (size_t)N * H;
    __half* zs  = (__half*)zr;
    float* dinv = zr + (size_t)N * O;
    int* cnt    = (int*)(dinv + N);
    int* rowptr = cnt + (N + 1);
    int* bsum   = rowptr + (N + 1);
    int* bcntg  = bsum + 512;
    int* esrc   = bcntg + 256;

    const int NBUK   = (N + 511) >> 9;          // 196
    const int nb_n1  = (N + 256) / 256;         // covers N+1 entries (391 <= 512)
    const int nb_bin = (E + EPB - 1) / EPB;     // 391

    k_init<<<1 + F * H / 256, 256, 0, stream>>>(bcntg, cnt, N, W1, W1t);
    k_bin<<<nb_bin, 256, 0, stream>>>(src, dst, bcntg, ebuf, E);
    k_bcount<<<NBUK, 256, 0, stream>>>(ebuf, bcntg, cnt, dinv, N);
    k_scan1<<<nb_n1, 256, 0, stream>>>(cnt, rowptr, bsum, N + 1);
    k_scan2<<<1, 512, 0, stream>>>(bsum, nb_n1);
    k_scan3<<<nb_n1, 256, 0, stream>>>(rowptr, bsum, N + 1);
    k_fillb<<<NBUK, 256, 0, stream>>>(ebuf, bcntg, rowptr, esrc, N);
    k_gemm1<<<(N + 63) / 64, 256, 0, stream>>>(x, W1t, dinv, y, N);
    k_gather1<<<(N + 3) / 4, 256, 0, stream>>>((const __half2*)y, rowptr, esrc,
                                               dinv, b1, (__half2*)h, N);
    k_zs<<<(N + 255) / 256, 256, 0, stream>>>(h, W2, dinv, zs, N);
    k_gather2<<<(N + 15) / 16, 256, 0, stream>>>(zs, rowptr, esrc, dinv, b2, out, N);
}

// Round 8
// 240.168 us; speedup vs baseline: 2.7533x; 1.0946x over previous
//
#include <hip/hip_runtime.h>
#include <hip/hip_fp16.h>

// GCN 2-layer forward on gfx950 — CSR-gather with fp16-compressed intermediates
// (fp32 accumulation), bucketed counting-sort CSR build (packed 4B entries),
// LDS-tiled fp32 GEMM. F=128 in, H=64 hidden, O=10 out. N=100k, E=1.6M.
static constexpr int F = 128;
static constexpr int H = 64;
static constexpr int O = 10;
static constexpr int PS = 12;          // padded zs row stride in halves (10 -> 12)
static constexpr int NBUK_MAX = 256;   // buckets of 512 nodes (dst>>9)
static constexpr int CAP = 12288;      // per-bucket edge capacity (avg ~8192)
static constexpr int EPB = 4096;       // edges per block in k_bin
static constexpr int TS = 132;         // bt LDS stride (128 + 4 pad)
static constexpr int XS = 68;          // xs LDS stride (64 + 4 pad)

// block 0: zero bcntg + scan pad; blocks 1..32: transpose W1 -> W1t (32KB).
__global__ __launch_bounds__(256) void k_init(int* __restrict__ bcntg,
                                              int* __restrict__ cnt, int n,
                                              const float* __restrict__ W1,
                                              float* __restrict__ W1t) {
    int b = blockIdx.x, t = threadIdx.x;
    if (b == 0) {
        bcntg[t] = 0;
        if (t == 0) cnt[n] = 0;
    } else {
        int i = (b - 1) * 256 + t;   // i < F*H = 8192
        int k = i >> 6, c = i & 63;
        W1t[c * F + k] = W1[k * H + c];
    }
}

// Bin edges by bucket = dst>>9. Per-block LDS histogram -> one global atomic
// reservation per (block,bucket) -> bucket-contiguous packed 4B writes:
// entry = (dst&511)<<17 | src   (src < 2^17).
__global__ __launch_bounds__(256) void k_bin(const int* __restrict__ src,
                                             const int* __restrict__ dst,
                                             int* __restrict__ bcntg,
                                             unsigned* __restrict__ ebuf, int e_total) {
    __shared__ int hist[NBUK_MAX];
    __shared__ int base[NBUK_MAX];
    __shared__ int loc[NBUK_MAX];
    int t = threadIdx.x;
    hist[t] = 0;
    loc[t] = 0;
    __syncthreads();
    int i0 = blockIdx.x * EPB;
    int i1 = min(i0 + EPB, e_total);
    int i = i0 + 4 * t;
    for (; i + 3 < i1; i += 1024) {
        int4 d4 = *(const int4*)&dst[i];
        atomicAdd(&hist[d4.x >> 9], 1);
        atomicAdd(&hist[d4.y >> 9], 1);
        atomicAdd(&hist[d4.z >> 9], 1);
        atomicAdd(&hist[d4.w >> 9], 1);
    }
    for (; i < i1; ++i) atomicAdd(&hist[dst[i] >> 9], 1);
    __syncthreads();
    if (hist[t] > 0) base[t] = atomicAdd(&bcntg[t], hist[t]);
    __syncthreads();
    i = i0 + 4 * t;
    for (; i + 3 < i1; i += 1024) {
        int4 s4 = *(const int4*)&src[i];
        int4 d4 = *(const int4*)&dst[i];
#pragma unroll
        for (int u = 0; u < 4; ++u) {
            int s = (&s4.x)[u], d = (&d4.x)[u];
            int b = d >> 9;
            int r = base[b] + atomicAdd(&loc[b], 1);
            if (r < CAP)
                ebuf[(size_t)b * CAP + r] = ((unsigned)(d & 511) << 17) | (unsigned)s;
        }
    }
    for (; i < i1; ++i) {
        int s = src[i], d = dst[i];
        int b = d >> 9;
        int r = base[b] + atomicAdd(&loc[b], 1);
        if (r < CAP)
            ebuf[(size_t)b * CAP + r] = ((unsigned)(d & 511) << 17) | (unsigned)s;
    }
}

// Per-bucket in-degree count (LDS counters) + dinv. One block per bucket.
__global__ __launch_bounds__(256) void k_bcount(const unsigned* __restrict__ ebuf,
                                                const int* __restrict__ bcntg,
                                                int* __restrict__ cnt,
                                                float* __restrict__ dinv, int n_nodes) {
    __shared__ int hc[512];
    int t = threadIdx.x, b = blockIdx.x, n0 = b << 9;
    hc[t] = 0;
    hc[t + 256] = 0;
    __syncthreads();
    int cb = bcntg[b];
    const unsigned* eb = ebuf + (size_t)b * CAP;
    int i = 4 * t;
    for (; i + 3 < cb; i += 1024) {
        uint4 e4 = *(const uint4*)&eb[i];
        atomicAdd(&hc[e4.x >> 17], 1);
        atomicAdd(&hc[e4.y >> 17], 1);
        atomicAdd(&hc[e4.z >> 17], 1);
        atomicAdd(&hc[e4.w >> 17], 1);
    }
    for (; i < cb; ++i) atomicAdd(&hc[eb[i] >> 17], 1);
    __syncthreads();
#pragma unroll
    for (int u = 0; u < 2; ++u) {
        int n = n0 + t + u * 256;
        if (n < n_nodes) {
            int c = hc[t + u * 256];
            cnt[n] = c;
            dinv[n] = rsqrtf((float)c + 1.0f);   // +1 self-loop
        }
    }
}

// Exclusive scan of cnt[0..n) (n = N+1 entries) -> rowptr, per-256 block + bsum.
__global__ __launch_bounds__(256) void k_scan1(const int* __restrict__ cnt,
                                               int* __restrict__ rowptr,
                                               int* __restrict__ bsum, int n) {
    __shared__ int s[256];
    int t = threadIdx.x;
    int i = blockIdx.x * 256 + t;
    int v = (i < n) ? cnt[i] : 0;
    s[t] = v;
    __syncthreads();
    for (int off = 1; off < 256; off <<= 1) {
        int x = (t >= off) ? s[t - off] : 0;
        __syncthreads();
        s[t] += x;
        __syncthreads();
    }
    if (i < n) rowptr[i] = s[t] - v;
    if (t == 255) bsum[blockIdx.x] = s[255];
}

__global__ __launch_bounds__(512) void k_scan2(int* __restrict__ bsum, int nb) {
    __shared__ int s[512];
    int t = threadIdx.x;
    int v = (t < nb) ? bsum[t] : 0;
    s[t] = v;
    __syncthreads();
    for (int off = 1; off < 512; off <<= 1) {
        int x = (t >= off) ? s[t - off] : 0;
        __syncthreads();
        s[t] += x;
        __syncthreads();
    }
    if (t < nb) bsum[t] = s[t] - v;
}

__global__ __launch_bounds__(256) void k_scan3(int* __restrict__ rowptr,
                                               const int* __restrict__ bsum, int n) {
    int i = blockIdx.x * 256 + threadIdx.x;
    if (i < n) rowptr[i] += bsum[blockIdx.x];
}

// Per-bucket CSR fill: LDS cursors, esrc writes confined to one ~34KB window per CU.
__global__ __launch_bounds__(256) void k_fillb(const unsigned* __restrict__ ebuf,
                                               const int* __restrict__ bcntg,
                                               const int* __restrict__ rowptr,
                                               int* __restrict__ esrc, int n_nodes) {
    __shared__ int curs[512];
    int t = threadIdx.x, b = blockIdx.x, n0 = b << 9;
#pragma unroll
    for (int u = 0; u < 2; ++u) {
        int n = n0 + t + u * 256;
        if (n < n_nodes) curs[t + u * 256] = rowptr[n];
    }
    __syncthreads();
    int cb = bcntg[b];
    const unsigned* eb = ebuf + (size_t)b * CAP;
    int i = 4 * t;
    for (; i + 3 < cb; i += 1024) {
        uint4 e4 = *(const uint4*)&eb[i];
#pragma unroll
        for (int u = 0; u < 4; ++u) {
            unsigned e = (&e4.x)[u];
            int r = atomicAdd(&curs[e >> 17], 1);
            esrc[r] = (int)(e & 0x1FFFFu);
        }
    }
    for (; i < cb; ++i) {
        unsigned e = eb[i];
        int r = atomicAdd(&curs[e >> 17], 1);
        esrc[r] = (int)(e & 0x1FFFFu);
    }
}

// y = fp16((x @ W1) * dinv[n]), LDS-tiled: 64-row tiles, W1^T resident in LDS,
// per-thread 4x4 register tile (rows/cols strided by 16 -> <=2-way LDS aliasing).
__global__ __launch_bounds__(256) void k_gemm1(
    const float* __restrict__ x, const float* __restrict__ W1t,
    const float* __restrict__ dinv, __half* __restrict__ y, int n_nodes) {
    __shared__ float bt[H * TS];   // [col][k], 33792 B
    __shared__ float xs[64 * XS];  // [row][k-half], 17408 B
    const int tid = threadIdx.x;
    const int rg = tid >> 4;       // 0..15
    const int cg = tid & 15;       // 0..15
    const int row0 = blockIdx.x * 64;

    for (int i = tid; i < H * (F / 4); i += 256) {
        int c = i >> 5, k4 = i & 31;
        float4 v = *(const float4*)&W1t[c * F + 4 * k4];
        *(float4*)&bt[c * TS + 4 * k4] = v;
    }

    float acc[4][4];
#pragma unroll
    for (int i = 0; i < 4; ++i)
#pragma unroll
        for (int j = 0; j < 4; ++j) acc[i][j] = 0.f;

    for (int kh = 0; kh < 2; ++kh) {
        __syncthreads();
        for (int i = tid; i < 64 * 16; i += 256) {
            int r = i >> 4, k4 = i & 15;
            int gr = row0 + r;
            float4 v = (gr < n_nodes)
                           ? *(const float4*)&x[(size_t)gr * F + kh * 64 + 4 * k4]
                           : make_float4(0.f, 0.f, 0.f, 0.f);
            *(float4*)&xs[r * XS + 4 * k4] = v;
        }
        __syncthreads();
#pragma unroll
        for (int k4 = 0; k4 < 16; ++k4) {
            float4 a[4], b[4];
#pragma unroll
            for (int c = 0; c < 4; ++c)
                a[c] = *(const float4*)&xs[(rg + 16 * c) * XS + 4 * k4];
#pragma unroll
            for (int c = 0; c < 4; ++c)
                b[c] = *(const float4*)&bt[(cg + 16 * c) * TS + kh * 64 + 4 * k4];
#pragma unroll
            for (int i = 0; i < 4; ++i)
#pragma unroll
                for (int j = 0; j < 4; ++j) {
                    acc[i][j] = fmaf(a[i].x, b[j].x, acc[i][j]);
                    acc[i][j] = fmaf(a[i].y, b[j].y, acc[i][j]);
                    acc[i][j] = fmaf(a[i].z, b[j].z, acc[i][j]);
                    acc[i][j] = fmaf(a[i].w, b[j].w, acc[i][j]);
                }
        }
    }
#pragma unroll
    for (int i = 0; i < 4; ++i) {
        int r = row0 + rg + 16 * i;
        if (r < n_nodes) {
            float d = dinv[r];
#pragma unroll
            for (int j = 0; j < 4; ++j)
                y[(size_t)r * H + cg + 16 * j] = __float2half(acc[i][j] * d);
        }
    }
}

// h[n] = fp16(relu(dinv[n]*(y[n] + sum_k y[esrc[k]]) + b1))
// Wave per node. Lane = (group g in [0,4), feature-quad c in [0,16)): each
// uint2 (4-halves) load covers 4 features x 4 edges/wave-instruction. Edge
// indices preloaded coalesced (deg<=64 fast path), fetched per step via shfl.
// 16 edges in flight per wave (unroll 4 x 4 groups).
__global__ __launch_bounds__(256) void k_gather1(
    const uint2* __restrict__ yq, const int* __restrict__ rowptr,
    const int* __restrict__ esrc, const float* __restrict__ dinv,
    const float* __restrict__ b1, uint2* __restrict__ hq, int n_nodes) {
    const int l = threadIdx.x & 63;
    const int g = l >> 4;          // edge-slot group (0..3)
    const int c = l & 15;          // feature-quad index
    const int n = blockIdx.x * 4 + (threadIdx.x >> 6);
    if (n >= n_nodes) return;
    const int beg = rowptr[n], end = rowptr[n + 1];
    const int deg = end - beg;
    int idx = (l < deg) ? esrc[beg + l] : 0;   // one coalesced preload
    float2 aA = make_float2(0.f, 0.f);         // features 4c, 4c+1
    float2 aB = make_float2(0.f, 0.f);         // features 4c+2, 4c+3
    if (g == 0) {                              // self-loop in group 0 only
        uint2 v = yq[(size_t)n * 16 + c];
        float2 fA = __half22float2(*(const __half2*)&v.x);
        float2 fB = __half22float2(*(const __half2*)&v.y);
        aA.x += fA.x; aA.y += fA.y; aB.x += fB.x; aB.y += fB.y;
    }
    const int dlim = min(deg, 64);
    int k = 0;
    for (; k + 15 < dlim; k += 16) {
#pragma unroll
        for (int u = 0; u < 4; ++u) {
            int s = __shfl(idx, k + 4 * u + g, 64);
            uint2 v = yq[(size_t)s * 16 + c];
            float2 fA = __half22float2(*(const __half2*)&v.x);
            float2 fB = __half22float2(*(const __half2*)&v.y);
            aA.x += fA.x; aA.y += fA.y; aB.x += fB.x; aB.y += fB.y;
        }
    }
    for (; k < dlim; k += 4) {
        int slot = k + g;
        int s = __shfl(idx, min(slot, dlim - 1), 64);
        if (slot < dlim) {
            uint2 v = yq[(size_t)s * 16 + c];
            float2 fA = __half22float2(*(const __half2*)&v.x);
            float2 fB = __half22float2(*(const __half2*)&v.y);
            aA.x += fA.x; aA.y += fA.y; aB.x += fB.x; aB.y += fB.y;
        }
    }
    for (int kk = 64 + g; kk < deg; kk += 4) {  // rare deg>64 fallback
        int s = esrc[beg + kk];
        uint2 v = yq[(size_t)s * 16 + c];
        float2 fA = __half22float2(*(const __half2*)&v.x);
        float2 fB = __half22float2(*(const __half2*)&v.y);
        aA.x += fA.x; aA.y += fA.y; aB.x += fB.x; aB.y += fB.y;
    }
#pragma unroll
    for (int off = 16; off <= 32; off <<= 1) {   // fold 4 edge groups
        aA.x += __shfl_xor(aA.x, off, 64);
        aA.y += __shfl_xor(aA.y, off, 64);
        aB.x += __shfl_xor(aB.x, off, 64);
        aB.y += __shfl_xor(aB.y, off, 64);
    }
    if (g == 0) {
        float4 bb = ((const float4*)b1)[c];
        float d = dinv[n];
        float h0 = fmaxf(fmaf(d, aA.x, bb.x), 0.0f);
        float h1 = fmaxf(fmaf(d, aA.y, bb.y), 0.0f);
        float h2 = fmaxf(fmaf(d, aB.x, bb.z), 0.0f);
        float h3 = fmaxf(fmaf(d, aB.y, bb.w), 0.0f);
        __half2 p0 = __floats2half2_rn(h0, h1);
        __half2 p1 = __floats2half2_rn(h2, h3);
        hq[(size_t)n * 16 + c] = make_uint2(*(const unsigned*)&p0, *(const unsigned*)&p1);
    }
}

// zs[n][j] = fp16(dinv[n] * (h[n] @ W2)[j]), row stride PS=12 halves.
// Thread per node: h row via __half2, W2 wave-uniform s_load; LDS-staged
// coalesced packed-uint output writes.
__global__ __launch_bounds__(256) void k_zs(
    const __half* __restrict__ h, const float* __restrict__ W2,
    const float* __restrict__ dinv, unsigned* __restrict__ zs_u, int n_nodes) {
    __shared__ unsigned zbuf[256 * (PS / 2)];   // 6 KB
    const int t = threadIdx.x;
    const int n0 = blockIdx.x * 256;
    const int n = n0 + t;
    if (n < n_nodes) {
        float acc[O];
#pragma unroll
        for (int j = 0; j < O; ++j) acc[j] = 0.f;
        const __half2* hr = (const __half2*)(h + (size_t)n * H);
#pragma unroll
        for (int k2 = 0; k2 < H / 2; ++k2) {
            float2 hv = __half22float2(hr[k2]);
#pragma unroll
            for (int j = 0; j < O; ++j) {
                acc[j] = fmaf(hv.x, W2[(2 * k2 + 0) * O + j], acc[j]);
                acc[j] = fmaf(hv.y, W2[(2 * k2 + 1) * O + j], acc[j]);
            }
        }
        float d = dinv[n];
#pragma unroll
        for (int q = 0; q < O / 2; ++q) {
            __half2 p = __floats2half2_rn(acc[2 * q] * d, acc[2 * q + 1] * d);
            zbuf[t * (PS / 2) + q] = *(const unsigned*)&p;
        }
        zbuf[t * (PS / 2) + 5] = 0u;   // pad
    }
    __syncthreads();
    int total = (min(n0 + 256, n_nodes) - n0) * (PS / 2);
    unsigned* zo = zs_u + (size_t)n0 * (PS / 2);
    for (int i = t; i < total; i += 256) zo[i] = zbuf[i];
}

// out[n][j] = dinv[n] * (zs[n][j] + sum_k zs[esrc[k]][j]) + b2[j]   (fp32 out)
// 8 lanes/node (5 active as half2 feature-pairs), 8 nodes/wave; edge indices
// chunk-preloaded (8 at a time) and broadcast via shfl within the subgroup.
__global__ __launch_bounds__(256) void k_gather2(
    const unsigned* __restrict__ zs_u, const int* __restrict__ rowptr,
    const int* __restrict__ esrc, const float* __restrict__ dinv,
    const float* __restrict__ b2, float* __restrict__ out, int n_nodes) {
    const int l = threadIdx.x & 63;
    const int j = l & 7;                    // lane within node subgroup
    const int sbase = l & ~7;               // subgroup base lane
    const int n = blockIdx.x * 32 + (threadIdx.x >> 3);
    if (n >= n_nodes) return;
    const int beg = rowptr[n], end = rowptr[n + 1];
    const int deg = end - beg;
    float2 acc = make_float2(0.f, 0.f);
    if (j < 5) {
        unsigned v = zs_u[(size_t)n * (PS / 2) + j];
        acc = __half22float2(*(const __half2*)&v);
    }
    for (int k0 = 0; k0 < deg; k0 += 8) {
        int idx = (k0 + j < deg) ? esrc[beg + k0 + j] : 0;
        int m = min(8, deg - k0);
        for (int e = 0; e < m; ++e) {
            int s = __shfl(idx, sbase + e, 64);
            if (j < 5) {
                unsigned v = zs_u[(size_t)s * (PS / 2) + j];
                float2 f = __half22float2(*(const __half2*)&v);
                acc.x += f.x;
                acc.y += f.y;
            }
        }
    }
    if (j < 5) {
        float2 bb = ((const float2*)b2)[j];
        float d = dinv[n];
        float2 o = make_float2(fmaf(d, acc.x, bb.x), fmaf(d, acc.y, bb.y));
        *(float2*)&out[(size_t)n * O + 2 * j] = o;
    }
}

extern "C" void kernel_launch(void* const* d_in, const int* in_sizes, int n_in,
                              void* d_out, int out_size, void* d_ws, size_t ws_size,
                              hipStream_t stream) {
    const float* x  = (const float*)d_in[0];
    const int*   ei = (const int*)d_in[1];
    const float* W1 = (const float*)d_in[2];
    const float* b1 = (const float*)d_in[3];
    const float* W2 = (const float*)d_in[4];
    const float* b2 = (const float*)d_in[5];
    float* out = (float*)d_out;

    const int N = in_sizes[0] / F;   // 100000
    const int E = in_sizes[1] / 2;   // 1600000
    const int* src = ei;
    const int* dst = ei + E;

    // Workspace (regions in fp32 units): y[N*H] | h-region[N*H] (front aliased
    // by ebuf 9.6MB, consumed before h written; tail 32KB = W1t) | zs[N*O]
    // (PS=12-half rows use N*6 floats of it) | dinv[N] | cnt[N+1] | rowptr[N+1]
    // | bsum[512] | bcntg[256] | esrc[E]
    float* yr   = (float*)d_ws;
    float* hr   = yr + (size_t)N * H;
    __half* y   = (__half*)yr;
    __half* h   = (__half*)hr;
    unsigned* ebuf = (unsigned*)hr;                // consumed before h is written
    float* W1t  = hr + (size_t)N * H - F * H;      // tail of h region, after ebuf
    float* zr   = hr + (size_t)N * H;
    unsigned* zs_u = (unsigned*)zr;                // N * PS/2 packed half2
    float* dinv = zr + (size_t)N * O;
    int* cnt    = (int*)(dinv + N);
    int* rowptr = cnt + (N + 1);
    int* bsum   = rowptr + (N + 1);
    int* bcntg  = bsum + 512;
    int* esrc   = bcntg + 256;

    const int NBUK   = (N + 511) >> 9;          // 196
    const int nb_n1  = (N + 256) / 256;         // covers N+1 entries (391 <= 512)
    const int nb_bin = (E + EPB - 1) / EPB;     // 391

    k_init<<<1 + F * H / 256, 256, 0, stream>>>(bcntg, cnt, N, W1, W1t);
    k_bin<<<nb_bin, 256, 0, stream>>>(src, dst, bcntg, ebuf, E);
    k_bcount<<<NBUK, 256, 0, stream>>>(ebuf, bcntg, cnt, dinv, N);
    k_scan1<<<nb_n1, 256, 0, stream>>>(cnt, rowptr, bsum, N + 1);
    k_scan2<<<1, 512, 0, stream>>>(bsum, nb_n1);
    k_scan3<<<nb_n1, 256, 0, stream>>>(rowptr, bsum, N + 1);
    k_fillb<<<NBUK, 256, 0, stream>>>(ebuf, bcntg, rowptr, esrc, N);
    k_gemm1<<<(N + 63) / 64, 256, 0, stream>>>(x, W1t, dinv, y, N);
    k_gather1<<<(N + 3) / 4, 256, 0, stream>>>((const uint2*)y, rowptr, esrc,
                                               dinv, b1, (uint2*)h, N);
    k_zs<<<(N + 255) / 256, 256, 0, stream>>>(h, W2, dinv, zs_u, N);
    k_gather2<<<(N + 31) / 32, 256, 0, stream>>>(zs_u, rowptr, esrc, dinv, b2, out, N);
}

// Round 9
// 220.019 us; speedup vs baseline: 3.0054x; 1.0916x over previous
//
#include <hip/hip_runtime.h>
#include <hip/hip_fp16.h>

// GCN 2-layer forward on gfx950 — CSR-gather with fp16-compressed intermediates
// (fp32 accumulation), bucketed counting-sort CSR build (packed 4B entries),
// MFMA (16x16x32 f16) layer-1 transform. F=128, H=64, O=10. N=100k, E=1.6M.
static constexpr int F = 128;
static constexpr int H = 64;
static constexpr int O = 10;
static constexpr int PS = 12;          // padded zs row stride in halves (10 -> 12)
static constexpr int NBUK_MAX = 256;   // buckets of 512 nodes (dst>>9)
static constexpr int CAP = 12288;      // per-bucket edge capacity (avg ~8192)
static constexpr int EPB = 4096;       // edges per block in k_bin
static constexpr int XPAD = 136;       // xh LDS row stride in halves (128 + 8)

typedef _Float16 half8 __attribute__((ext_vector_type(8)));
typedef float floatx4 __attribute__((ext_vector_type(4)));

// block 0: zero bcntg + scan pad; blocks 1..32: build W1f = fp16 W1 in MFMA
// B-fragment order: W1f[((s*4+c)*64+lane)*8+j] = W1[(s*32+(lane>>4)*8+j)*H + c*16+(lane&15)]
__global__ __launch_bounds__(256) void k_init(int* __restrict__ bcntg,
                                              int* __restrict__ cnt, int n,
                                              const float* __restrict__ W1,
                                              __half* __restrict__ W1f) {
    int b = blockIdx.x, t = threadIdx.x;
    if (b == 0) {
        bcntg[t] = 0;
        if (t == 0) cnt[n] = 0;
    } else {
        int i = (b - 1) * 256 + t;   // 0..8191
        int j = i & 7, lane = (i >> 3) & 63, sc = i >> 9;
        int s = sc >> 2, c = sc & 3;
        int k = s * 32 + (lane >> 4) * 8 + j;
        int nn = c * 16 + (lane & 15);
        W1f[i] = __float2half(W1[k * H + nn]);
    }
}

// Bin edges by bucket = dst>>9. Per-block LDS histogram -> one global atomic
// reservation per (block,bucket) -> bucket-contiguous packed 4B writes:
// entry = (dst&511)<<17 | src   (src < 2^17).
__global__ __launch_bounds__(256) void k_bin(const int* __restrict__ src,
                                             const int* __restrict__ dst,
                                             int* __restrict__ bcntg,
                                             unsigned* __restrict__ ebuf, int e_total) {
    __shared__ int hist[NBUK_MAX];
    __shared__ int base[NBUK_MAX];
    __shared__ int loc[NBUK_MAX];
    int t = threadIdx.x;
    hist[t] = 0;
    loc[t] = 0;
    __syncthreads();
    int i0 = blockIdx.x * EPB;
    int i1 = min(i0 + EPB, e_total);
    int i = i0 + 4 * t;
    for (; i + 3 < i1; i += 1024) {
        int4 d4 = *(const int4*)&dst[i];
        atomicAdd(&hist[d4.x >> 9], 1);
        atomicAdd(&hist[d4.y >> 9], 1);
        atomicAdd(&hist[d4.z >> 9], 1);
        atomicAdd(&hist[d4.w >> 9], 1);
    }
    for (; i < i1; ++i) atomicAdd(&hist[dst[i] >> 9], 1);
    __syncthreads();
    if (hist[t] > 0) base[t] = atomicAdd(&bcntg[t], hist[t]);
    __syncthreads();
    i = i0 + 4 * t;
    for (; i + 3 < i1; i += 1024) {
        int4 s4 = *(const int4*)&src[i];
        int4 d4 = *(const int4*)&dst[i];
#pragma unroll
        for (int u = 0; u < 4; ++u) {
            int s = (&s4.x)[u], d = (&d4.x)[u];
            int b = d >> 9;
            int r = base[b] + atomicAdd(&loc[b], 1);
            if (r < CAP)
                ebuf[(size_t)b * CAP + r] = ((unsigned)(d & 511) << 17) | (unsigned)s;
        }
    }
    for (; i < i1; ++i) {
        int s = src[i], d = dst[i];
        int b = d >> 9;
        int r = base[b] + atomicAdd(&loc[b], 1);
        if (r < CAP)
            ebuf[(size_t)b * CAP + r] = ((unsigned)(d & 511) << 17) | (unsigned)s;
    }
}

// Per-bucket in-degree count (LDS counters) + dinv. One block per bucket.
__global__ __launch_bounds__(256) void k_bcount(const unsigned* __restrict__ ebuf,
                                                const int* __restrict__ bcntg,
                                                int* __restrict__ cnt,
                                                float* __restrict__ dinv, int n_nodes) {
    __shared__ int hc[512];
    int t = threadIdx.x, b = blockIdx.x, n0 = b << 9;
    hc[t] = 0;
    hc[t + 256] = 0;
    __syncthreads();
    int cb = bcntg[b];
    const unsigned* eb = ebuf + (size_t)b * CAP;
    int i = 4 * t;
    for (; i + 3 < cb; i += 1024) {
        uint4 e4 = *(const uint4*)&eb[i];
        atomicAdd(&hc[e4.x >> 17], 1);
        atomicAdd(&hc[e4.y >> 17], 1);
        atomicAdd(&hc[e4.z >> 17], 1);
        atomicAdd(&hc[e4.w >> 17], 1);
    }
    for (; i < cb; ++i) atomicAdd(&hc[eb[i] >> 17], 1);
    __syncthreads();
#pragma unroll
    for (int u = 0; u < 2; ++u) {
        int n = n0 + t + u * 256;
        if (n < n_nodes) {
            int c = hc[t + u * 256];
            cnt[n] = c;
            dinv[n] = rsqrtf((float)c + 1.0f);   // +1 self-loop
        }
    }
}

// Exclusive scan of cnt[0..n) (n = N+1 entries) -> rowptr, per-256 block + bsum.
__global__ __launch_bounds__(256) void k_scan1(const int* __restrict__ cnt,
                                               int* __restrict__ rowptr,
                                               int* __restrict__ bsum, int n) {
    __shared__ int s[256];
    int t = threadIdx.x;
    int i = blockIdx.x * 256 + t;
    int v = (i < n) ? cnt[i] : 0;
    s[t] = v;
    __syncthreads();
    for (int off = 1; off < 256; off <<= 1) {
        int x = (t >= off) ? s[t - off] : 0;
        __syncthreads();
        s[t] += x;
        __syncthreads();
    }
    if (i < n) rowptr[i] = s[t] - v;
    if (t == 255) bsum[blockIdx.x] = s[255];
}

__global__ __launch_bounds__(512) void k_scan2(int* __restrict__ bsum, int nb) {
    __shared__ int s[512];
    int t = threadIdx.x;
    int v = (t < nb) ? bsum[t] : 0;
    s[t] = v;
    __syncthreads();
    for (int off = 1; off < 512; off <<= 1) {
        int x = (t >= off) ? s[t - off] : 0;
        __syncthreads();
        s[t] += x;
        __syncthreads();
    }
    if (t < nb) bsum[t] = s[t] - v;
}

__global__ __launch_bounds__(256) void k_scan3(int* __restrict__ rowptr,
                                               const int* __restrict__ bsum, int n) {
    int i = blockIdx.x * 256 + threadIdx.x;
    if (i < n) rowptr[i] += bsum[blockIdx.x];
}

// Per-bucket CSR fill: LDS cursors, esrc writes confined to one ~34KB window per CU.
__global__ __launch_bounds__(256) void k_fillb(const unsigned* __restrict__ ebuf,
                                               const int* __restrict__ bcntg,
                                               const int* __restrict__ rowptr,
                                               int* __restrict__ esrc, int n_nodes) {
    __shared__ int curs[512];
    int t = threadIdx.x, b = blockIdx.x, n0 = b << 9;
#pragma unroll
    for (int u = 0; u < 2; ++u) {
        int n = n0 + t + u * 256;
        if (n < n_nodes) curs[t + u * 256] = rowptr[n];
    }
    __syncthreads();
    int cb = bcntg[b];
    const unsigned* eb = ebuf + (size_t)b * CAP;
    int i = 4 * t;
    for (; i + 3 < cb; i += 1024) {
        uint4 e4 = *(const uint4*)&eb[i];
#pragma unroll
        for (int u = 0; u < 4; ++u) {
            unsigned e = (&e4.x)[u];
            int r = atomicAdd(&curs[e >> 17], 1);
            esrc[r] = (int)(e & 0x1FFFFu);
        }
    }
    for (; i < cb; ++i) {
        unsigned e = eb[i];
        int r = atomicAdd(&curs[e >> 17], 1);
        esrc[r] = (int)(e & 0x1FFFFu);
    }
}

// y = fp16((x @ W1) * dinv[n]) via MFMA 16x16x32 f16. Block = 4 waves = 64 rows.
// B (all of W1) lives in 64 VGPRs/lane, fragment-ordered (W1f). A staged fp16
// in LDS; 4 ds_read_b128 + 16 MFMA per wave. C layout: col=lane&15, row=quad*4+reg.
__global__ __launch_bounds__(256, 4) void k_gemm1(
    const float* __restrict__ x, const __half* __restrict__ W1f,
    const float* __restrict__ dinv, __half* __restrict__ y, int n_nodes) {
    __shared__ __half xh[64 * XPAD];
    const int tid = threadIdx.x;
    const int lane = tid & 63;
    const int w = tid >> 6;
    const int row0 = blockIdx.x * 64;

    // preload all 16 B-fragments (coalesced, L2-hot)
    half8 bf[16];
    const uint4* wf = (const uint4*)W1f;
#pragma unroll
    for (int sc = 0; sc < 16; ++sc) {
        union { uint4 u; half8 h; } tmp;
        tmp.u = wf[sc * 64 + lane];
        bf[sc] = tmp.h;
    }

    // stage x tile -> fp16 LDS
    for (int i = tid; i < 64 * 32; i += 256) {
        int r = i >> 5, k4 = i & 31;
        int gr = row0 + r;
        if (gr < n_nodes) {
            float4 v = *(const float4*)&x[(size_t)gr * F + 4 * k4];
            __half2 p0 = __floats2half2_rn(v.x, v.y);
            __half2 p1 = __floats2half2_rn(v.z, v.w);
            uint2 pk = make_uint2(*(unsigned*)&p0, *(unsigned*)&p1);
            *(uint2*)&xh[r * XPAD + 4 * k4] = pk;
        }
    }
    __syncthreads();

    const int m16 = lane & 15, quad = lane >> 4;
    floatx4 acc[4];
#pragma unroll
    for (int c = 0; c < 4; ++c) acc[c] = (floatx4){0.f, 0.f, 0.f, 0.f};
#pragma unroll
    for (int s = 0; s < 4; ++s) {
        union { uint4 u; half8 h; } ua;
        ua.u = *(const uint4*)&xh[(16 * w + m16) * XPAD + s * 32 + quad * 8];
#pragma unroll
        for (int c = 0; c < 4; ++c)
            acc[c] = __builtin_amdgcn_mfma_f32_16x16x32_f16(ua.h, bf[s * 4 + c],
                                                            acc[c], 0, 0, 0);
    }
#pragma unroll
    for (int r = 0; r < 4; ++r) {
        int grow = row0 + 16 * w + quad * 4 + r;
        if (grow < n_nodes) {
            float d = dinv[grow];
#pragma unroll
            for (int c = 0; c < 4; ++c)
                y[(size_t)grow * H + c * 16 + m16] = __float2half(acc[c][r] * d);
        }
    }
}

// h[n] = fp16(relu(dinv[n]*(y[n] + sum_k y[esrc[k]]) + b1))
// Wave per node. Lane = (group g in [0,4), feature-quad c in [0,16)): each
// uint2 (4-halves) load covers 4 features x 4 edges/wave-instruction. Edge
// indices preloaded coalesced (deg<=64 fast path), fetched per step via shfl.
__global__ __launch_bounds__(256) void k_gather1(
    const uint2* __restrict__ yq, const int* __restrict__ rowptr,
    const int* __restrict__ esrc, const float* __restrict__ dinv,
    const float* __restrict__ b1, uint2* __restrict__ hq, int n_nodes) {
    const int l = threadIdx.x & 63;
    const int g = l >> 4;          // edge-slot group (0..3)
    const int c = l & 15;          // feature-quad index
    const int n = blockIdx.x * 4 + (threadIdx.x >> 6);
    if (n >= n_nodes) return;
    const int beg = rowptr[n], end = rowptr[n + 1];
    const int deg = end - beg;
    int idx = (l < deg) ? esrc[beg + l] : 0;   // one coalesced preload
    float2 aA = make_float2(0.f, 0.f);         // features 4c, 4c+1
    float2 aB = make_float2(0.f, 0.f);         // features 4c+2, 4c+3
    if (g == 0) {                              // self-loop in group 0 only
        uint2 v = yq[(size_t)n * 16 + c];
        float2 fA = __half22float2(*(const __half2*)&v.x);
        float2 fB = __half22float2(*(const __half2*)&v.y);
        aA.x += fA.x; aA.y += fA.y; aB.x += fB.x; aB.y += fB.y;
    }
    const int dlim = min(deg, 64);
    int k = 0;
    for (; k + 15 < dlim; k += 16) {
#pragma unroll
        for (int u = 0; u < 4; ++u) {
            int s = __shfl(idx, k + 4 * u + g, 64);
            uint2 v = yq[(size_t)s * 16 + c];
            float2 fA = __half22float2(*(const __half2*)&v.x);
            float2 fB = __half22float2(*(const __half2*)&v.y);
            aA.x += fA.x; aA.y += fA.y; aB.x += fB.x; aB.y += fB.y;
        }
    }
    for (; k < dlim; k += 4) {
        int slot = k + g;
        int s = __shfl(idx, min(slot, dlim - 1), 64);
        if (slot < dlim) {
            uint2 v = yq[(size_t)s * 16 + c];
            float2 fA = __half22float2(*(const __half2*)&v.x);
            float2 fB = __half22float2(*(const __half2*)&v.y);
            aA.x += fA.x; aA.y += fA.y; aB.x += fB.x; aB.y += fB.y;
        }
    }
    for (int kk = 64 + g; kk < deg; kk += 4) {  // rare deg>64 fallback
        int s = esrc[beg + kk];
        uint2 v = yq[(size_t)s * 16 + c];
        float2 fA = __half22float2(*(const __half2*)&v.x);
        float2 fB = __half22float2(*(const __half2*)&v.y);
        aA.x += fA.x; aA.y += fA.y; aB.x += fB.x; aB.y += fB.y;
    }
#pragma unroll
    for (int off = 16; off <= 32; off <<= 1) {   // fold 4 edge groups
        aA.x += __shfl_xor(aA.x, off, 64);
        aA.y += __shfl_xor(aA.y, off, 64);
        aB.x += __shfl_xor(aB.x, off, 64);
        aB.y += __shfl_xor(aB.y, off, 64);
    }
    if (g == 0) {
        float4 bb = ((const float4*)b1)[c];
        float d = dinv[n];
        float h0 = fmaxf(fmaf(d, aA.x, bb.x), 0.0f);
        float h1 = fmaxf(fmaf(d, aA.y, bb.y), 0.0f);
        float h2 = fmaxf(fmaf(d, aB.x, bb.z), 0.0f);
        float h3 = fmaxf(fmaf(d, aB.y, bb.w), 0.0f);
        __half2 p0 = __floats2half2_rn(h0, h1);
        __half2 p1 = __floats2half2_rn(h2, h3);
        hq[(size_t)n * 16 + c] = make_uint2(*(const unsigned*)&p0, *(const unsigned*)&p1);
    }
}

// zs[n][j] = fp16(dinv[n] * (h[n] @ W2)[j]), row stride PS=12 halves.
__global__ __launch_bounds__(256) void k_zs(
    const __half* __restrict__ h, const float* __restrict__ W2,
    const float* __restrict__ dinv, unsigned* __restrict__ zs_u, int n_nodes) {
    __shared__ unsigned zbuf[256 * (PS / 2)];   // 6 KB
    const int t = threadIdx.x;
    const int n0 = blockIdx.x * 256;
    const int n = n0 + t;
    if (n < n_nodes) {
        float acc[O];
#pragma unroll
        for (int j = 0; j < O; ++j) acc[j] = 0.f;
        const __half2* hr = (const __half2*)(h + (size_t)n * H);
#pragma unroll
        for (int k2 = 0; k2 < H / 2; ++k2) {
            float2 hv = __half22float2(hr[k2]);
#pragma unroll
            for (int j = 0; j < O; ++j) {
                acc[j] = fmaf(hv.x, W2[(2 * k2 + 0) * O + j], acc[j]);
                acc[j] = fmaf(hv.y, W2[(2 * k2 + 1) * O + j], acc[j]);
            }
        }
        float d = dinv[n];
#pragma unroll
        for (int q = 0; q < O / 2; ++q) {
            __half2 p = __floats2half2_rn(acc[2 * q] * d, acc[2 * q + 1] * d);
            zbuf[t * (PS / 2) + q] = *(const unsigned*)&p;
        }
        zbuf[t * (PS / 2) + 5] = 0u;   // pad
    }
    __syncthreads();
    int total = (min(n0 + 256, n_nodes) - n0) * (PS / 2);
    unsigned* zo = zs_u + (size_t)n0 * (PS / 2);
    for (int i = t; i < total; i += 256) zo[i] = zbuf[i];
}

// out[n][j] = dinv[n] * (zs[n][j] + sum_k zs[esrc[k]][j]) + b2[j]   (fp32 out)
__global__ __launch_bounds__(256) void k_gather2(
    const unsigned* __restrict__ zs_u, const int* __restrict__ rowptr,
    const int* __restrict__ esrc, const float* __restrict__ dinv,
    const float* __restrict__ b2, float* __restrict__ out, int n_nodes) {
    const int l = threadIdx.x & 63;
    const int j = l & 7;                    // lane within node subgroup
    const int sbase = l & ~7;               // subgroup base lane
    const int n = blockIdx.x * 32 + (threadIdx.x >> 3);
    if (n >= n_nodes) return;
    const int beg = rowptr[n], end = rowptr[n + 1];
    const int deg = end - beg;
    float2 acc = make_float2(0.f, 0.f);
    if (j < 5) {
        unsigned v = zs_u[(size_t)n * (PS / 2) + j];
        acc = __half22float2(*(const __half2*)&v);
    }
    for (int k0 = 0; k0 < deg; k0 += 8) {
        int idx = (k0 + j < deg) ? esrc[beg + k0 + j] : 0;
        int m = min(8, deg - k0);
        for (int e = 0; e < m; ++e) {
            int s = __shfl(idx, sbase + e, 64);
            if (j < 5) {
                unsigned v = zs_u[(size_t)s * (PS / 2) + j];
                float2 f = __half22float2(*(const __half2*)&v);
                acc.x += f.x;
                acc.y += f.y;
            }
        }
    }
    if (j < 5) {
        float2 bb = ((const float2*)b2)[j];
        float d = dinv[n];
        float2 o = make_float2(fmaf(d, acc.x, bb.x), fmaf(d, acc.y, bb.y));
        *(float2*)&out[(size_t)n * O + 2 * j] = o;
    }
}

extern "C" void kernel_launch(void* const* d_in, const int* in_sizes, int n_in,
                              void* d_out, int out_size, void* d_ws, size_t ws_size,
                              hipStream_t stream) {
    const float* x  = (const float*)d_in[0];
    const int*   ei = (const int*)d_in[1];
    const float* W1 = (const float*)d_in[2];
    const float* b1 = (const float*)d_in[3];
    const float* W2 = (const float*)d_in[4];
    const float* b2 = (const float*)d_in[5];
    float* out = (float*)d_out;

    const int N = in_sizes[0] / F;   // 100000
    const int E = in_sizes[1] / 2;   // 1600000
    const int* src = ei;
    const int* dst = ei + E;

    // Workspace (regions in fp32 units): y[N*H] | h-region[N*H] (front aliased
    // by ebuf 9.6MB, consumed before h written; tail 32KB = W1f fp16 16KB) |
    // zs[N*O] (PS=12-half rows) | dinv[N] | cnt[N+1] | rowptr[N+1] | bsum[512]
    // | bcntg[256] | esrc[E]
    float* yr   = (float*)d_ws;
    float* hr   = yr + (size_t)N * H;
    __half* y   = (__half*)yr;
    __half* h   = (__half*)hr;
    unsigned* ebuf = (unsigned*)hr;                // consumed before h is written
    __half* W1f = (__half*)(hr + (size_t)N * H - F * H);  // tail of h region
    float* zr   = hr + (size_t)N * H;
    unsigned* zs_u = (unsigned*)zr;                // N * PS/2 packed half2
    float* dinv = zr + (size_t)N * O;
    int* cnt    = (int*)(dinv + N);
    int* rowptr = cnt + (N + 1);
    int* bsum   = rowptr + (N + 1);
    int* bcntg  = bsum + 512;
    int* esrc   = bcntg + 256;

    const int NBUK   = (N + 511) >> 9;          // 196
    const int nb_n1  = (N + 256) / 256;         // covers N+1 entries (391 <= 512)
    const int nb_bin = (E + EPB - 1) / EPB;     // 391

    k_init<<<1 + F * H / 256, 256, 0, stream>>>(bcntg, cnt, N, W1, W1f);
    k_bin<<<nb_bin, 256, 0, stream>>>(src, dst, bcntg, ebuf, E);
    k_bcount<<<NBUK, 256, 0, stream>>>(ebuf, bcntg, cnt, dinv, N);
    k_scan1<<<nb_n1, 256, 0, stream>>>(cnt, rowptr, bsum, N + 1);
    k_scan2<<<1, 512, 0, stream>>>(bsum, nb_n1);
    k_scan3<<<nb_n1, 256, 0, stream>>>(rowptr, bsum, N + 1);
    k_fillb<<<NBUK, 256, 0, stream>>>(ebuf, bcntg, rowptr, esrc, N);
    k_gemm1<<<(N + 63) / 64, 256, 0, stream>>>(x, W1f, dinv, y, N);
    k_gather1<<<(N + 3) / 4, 256, 0, stream>>>((const uint2*)y, rowptr, esrc,
                                               dinv, b1, (uint2*)h, N);
    k_zs<<<(N + 255) / 256, 256, 0, stream>>>(h, W2, dinv, zs_u, N);
    k_gather2<<<(N + 31) / 32, 256, 0, stream>>>(zs_u, rowptr, esrc, dinv, b2, out, N);
}

// Round 11
// 199.901 us; speedup vs baseline: 3.3079x; 1.1006x over previous
//
#include <hip/hip_runtime.h>
#include <hip/hip_fp16.h>

// GCN 2-layer forward on gfx950 — CSR-gather with fp16 intermediates (fp32
// accumulation), single-kernel bucketed CSR build with 16-padded edge lists
// (dummy node N has all-zero rows), MFMA layer-1 transform.
// F=128, H=64, O=10. N=100k, E=1.6M.
static constexpr int F = 128;
static constexpr int H = 64;
static constexpr int O = 10;
static constexpr int PSU = 6;          // zs row stride in uints (12 halves, [5]=0 pad)
static constexpr int NBUK_MAX = 256;   // buckets of 512 nodes (dst>>9)
static constexpr int CAP = 12288;      // per-bucket RAW edge capacity (mean 8192, 45σ)
static constexpr int ESCAP = 14336;    // per-bucket PADDED esrc capacity
                                       // (padded mean ~11.7k, σ~180 -> ~14σ headroom;
                                       // R9 bug: padded lists overflowed CAP)
static constexpr int EPB = 4096;       // edges per block in k_bin
static constexpr int XPAD = 136;       // xh LDS row stride in halves (128 + 8)

typedef _Float16 half8 __attribute__((ext_vector_type(8)));
typedef float floatx4 __attribute__((ext_vector_type(4)));

// block 0: zero bcntg + zero dummy rows (y row N, zs row N);
// blocks 1..32: build W1f = fp16 W1 in MFMA B-fragment order.
__global__ __launch_bounds__(256) void k_init(int* __restrict__ bcntg,
                                              const float* __restrict__ W1,
                                              __half* __restrict__ W1f,
                                              unsigned* __restrict__ yN,
                                              unsigned* __restrict__ zsN) {
    int b = blockIdx.x, t = threadIdx.x;
    if (b == 0) {
        bcntg[t] = 0;
        if (t < 32) yN[t] = 0u;      // y row N: 64 halves
        if (t < PSU) zsN[t] = 0u;    // zs row N
    } else {
        int i = (b - 1) * 256 + t;   // 0..8191
        int j = i & 7, lane = (i >> 3) & 63, sc = i >> 9;
        int s = sc >> 2, c = sc & 3;
        int k = s * 32 + (lane >> 4) * 8 + j;
        int nn = c * 16 + (lane & 15);
        W1f[i] = __float2half(W1[k * H + nn]);
    }
}

// Bin edges by bucket = dst>>9; bucket-contiguous packed 4B entries:
// entry = (dst&511)<<17 | src   (src < 2^17).
__global__ __launch_bounds__(256) void k_bin(const int* __restrict__ src,
                                             const int* __restrict__ dst,
                                             int* __restrict__ bcntg,
                                             unsigned* __restrict__ ebuf, int e_total) {
    __shared__ int hist[NBUK_MAX];
    __shared__ int base[NBUK_MAX];
    __shared__ int loc[NBUK_MAX];
    int t = threadIdx.x;
    hist[t] = 0;
    loc[t] = 0;
    __syncthreads();
    int i0 = blockIdx.x * EPB;
    int i1 = min(i0 + EPB, e_total);
    int i = i0 + 4 * t;
    for (; i + 3 < i1; i += 1024) {
        int4 d4 = *(const int4*)&dst[i];
        atomicAdd(&hist[d4.x >> 9], 1);
        atomicAdd(&hist[d4.y >> 9], 1);
        atomicAdd(&hist[d4.z >> 9], 1);
        atomicAdd(&hist[d4.w >> 9], 1);
    }
    for (; i < i1; ++i) atomicAdd(&hist[dst[i] >> 9], 1);
    __syncthreads();
    if (hist[t] > 0) base[t] = atomicAdd(&bcntg[t], hist[t]);
    __syncthreads();
    i = i0 + 4 * t;
    for (; i + 3 < i1; i += 1024) {
        int4 s4 = *(const int4*)&src[i];
        int4 d4 = *(const int4*)&dst[i];
#pragma unroll
        for (int u = 0; u < 4; ++u) {
            int s = (&s4.x)[u], d = (&d4.x)[u];
            int b = d >> 9;
            int r = base[b] + atomicAdd(&loc[b], 1);
            if (r < CAP)
                ebuf[(size_t)b * CAP + r] = ((unsigned)(d & 511) << 17) | (unsigned)s;
        }
    }
    for (; i < i1; ++i) {
        int s = src[i], d = dst[i];
        int b = d >> 9;
        int r = base[b] + atomicAdd(&loc[b], 1);
        if (r < CAP)
            ebuf[(size_t)b * CAP + r] = ((unsigned)(d & 511) << 17) | (unsigned)s;
    }
}

// One block per bucket: count in-degrees (LDS), LDS-scan 16-padded counts,
// scatter src into bucket-padded esrc (stride ESCAP), pad with dummy node N.
// Emits rowbeg[n] (absolute into esrc), degp[n] (16-padded), dinv[n].
__global__ __launch_bounds__(256) void k_bsort(
    const unsigned* __restrict__ ebuf, const int* __restrict__ bcntg,
    int* __restrict__ rowbeg, int* __restrict__ degp, float* __restrict__ dinv,
    int* __restrict__ esrc, int n_nodes) {
    __shared__ int hc[512];
    __shared__ int sa[512];
    __shared__ int sb[512];
    int t = threadIdx.x, b = blockIdx.x, n0 = b << 9;
    hc[t] = 0;
    hc[t + 256] = 0;
    __syncthreads();
    int cb = min(bcntg[b], CAP);
    const unsigned* eb = ebuf + (size_t)b * CAP;
    int i = 4 * t;
    for (; i + 3 < cb; i += 1024) {
        uint4 e4 = *(const uint4*)&eb[i];
        atomicAdd(&hc[e4.x >> 17], 1);
        atomicAdd(&hc[e4.y >> 17], 1);
        atomicAdd(&hc[e4.z >> 17], 1);
        atomicAdd(&hc[e4.w >> 17], 1);
    }
    for (; i < cb; ++i) atomicAdd(&hc[eb[i] >> 17], 1);
    __syncthreads();
#pragma unroll
    for (int u = 0; u < 2; ++u) {
        int ii = t + 256 * u;
        sa[ii] = (hc[ii] + 15) & ~15;   // 16-padded count
    }
    __syncthreads();
    // Hillis-Steele inclusive scan over 512 entries (double-buffered)
    int* A = sa;
    int* Bp = sb;
    for (int off = 1; off < 512; off <<= 1) {
#pragma unroll
        for (int u = 0; u < 2; ++u) {
            int ii = t + 256 * u;
            int v = A[ii];
            if (ii >= off) v += A[ii - off];
            Bp[ii] = v;
        }
        __syncthreads();
        int* tmp = A; A = Bp; Bp = tmp;
    }
    // A = inclusive scan of padded counts; Bp = free buffer -> cursors
#pragma unroll
    for (int u = 0; u < 2; ++u) {
        int ii = t + 256 * u;
        int cnt = hc[ii];
        int cp = (cnt + 15) & ~15;
        int excl = A[ii] - cp;
        Bp[ii] = excl;                  // scatter cursor (bucket-local)
        int n = n0 + ii;
        if (n < n_nodes) {
            rowbeg[n] = b * ESCAP + excl;
            degp[n] = cp;
            dinv[n] = rsqrtf((float)cnt + 1.0f);   // true degree + self-loop
        }
    }
    __syncthreads();
    int* es = esrc + (size_t)b * ESCAP;
    i = 4 * t;
    for (; i + 3 < cb; i += 1024) {
        uint4 e4 = *(const uint4*)&eb[i];
#pragma unroll
        for (int u = 0; u < 4; ++u) {
            unsigned e = (&e4.x)[u];
            int r = atomicAdd(&Bp[e >> 17], 1);
            es[r] = (int)(e & 0x1FFFFu);
        }
    }
    for (; i < cb; ++i) {
        unsigned e = eb[i];
        int r = atomicAdd(&Bp[e >> 17], 1);
        es[r] = (int)(e & 0x1FFFFu);
    }
    __syncthreads();
#pragma unroll
    for (int u = 0; u < 2; ++u) {
        int ii = t + 256 * u;
        int end = A[ii];                          // excl + padded count
        for (int p = Bp[ii]; p < end; ++p) es[p] = n_nodes;   // dummy pad
    }
}

// y = fp16((x @ W1) * dinv[n]) via MFMA 16x16x32 f16. Block = 4 waves = 64 rows.
__global__ __launch_bounds__(256, 4) void k_gemm1(
    const float* __restrict__ x, const __half* __restrict__ W1f,
    const float* __restrict__ dinv, __half* __restrict__ y, int n_nodes) {
    __shared__ __half xh[64 * XPAD];
    const int tid = threadIdx.x;
    const int lane = tid & 63;
    const int w = tid >> 6;
    const int row0 = blockIdx.x * 64;

    half8 bf[16];
    const uint4* wf = (const uint4*)W1f;
#pragma unroll
    for (int sc = 0; sc < 16; ++sc) {
        union { uint4 u; half8 h; } tmp;
        tmp.u = wf[sc * 64 + lane];
        bf[sc] = tmp.h;
    }

    for (int i = tid; i < 64 * 32; i += 256) {
        int r = i >> 5, k4 = i & 31;
        int gr = row0 + r;
        if (gr < n_nodes) {
            float4 v = *(const float4*)&x[(size_t)gr * F + 4 * k4];
            __half2 p0 = __floats2half2_rn(v.x, v.y);
            __half2 p1 = __floats2half2_rn(v.z, v.w);
            uint2 pk = make_uint2(*(unsigned*)&p0, *(unsigned*)&p1);
            *(uint2*)&xh[r * XPAD + 4 * k4] = pk;
        }
    }
    __syncthreads();

    const int m16 = lane & 15, quad = lane >> 4;
    floatx4 acc[4];
#pragma unroll
    for (int c = 0; c < 4; ++c) acc[c] = (floatx4){0.f, 0.f, 0.f, 0.f};
#pragma unroll
    for (int s = 0; s < 4; ++s) {
        union { uint4 u; half8 h; } ua;
        ua.u = *(const uint4*)&xh[(16 * w + m16) * XPAD + s * 32 + quad * 8];
#pragma unroll
        for (int c = 0; c < 4; ++c)
            acc[c] = __builtin_amdgcn_mfma_f32_16x16x32_f16(ua.h, bf[s * 4 + c],
                                                            acc[c], 0, 0, 0);
    }
#pragma unroll
    for (int r = 0; r < 4; ++r) {
        int grow = row0 + 16 * w + quad * 4 + r;
        if (grow < n_nodes) {
            float d = dinv[grow];
#pragma unroll
            for (int c = 0; c < 4; ++c)
                y[(size_t)grow * H + c * 16 + m16] = __float2half(acc[c][r] * d);
        }
    }
}

// h[n] = fp16(relu(dinv[n]*(y[n] + sum_k y[esrc[k]]) + b1))
// Wave per node; lane = (group g in [0,4), feature-quad c in [0,16)).
// degp is a multiple of 16 -> branch-free inner loop, 16 edges in flight.
__global__ __launch_bounds__(256) void k_gather1(
    const uint2* __restrict__ yq, const int* __restrict__ rowbeg,
    const int* __restrict__ degp, const int* __restrict__ esrc,
    const float* __restrict__ dinv, const float* __restrict__ b1,
    uint2* __restrict__ hq, int n_nodes) {
    const int l = threadIdx.x & 63;
    const int g = l >> 4;
    const int c = l & 15;
    const int n = blockIdx.x * 4 + (threadIdx.x >> 6);
    if (n >= n_nodes) return;
    const int beg = rowbeg[n];
    const int dp = degp[n];
    const int idx = esrc[beg + l];             // coalesced preload (slots >= dp unused)
    float2 aA = make_float2(0.f, 0.f);
    float2 aB = make_float2(0.f, 0.f);
    if (g == 0) {                              // self-loop in group 0 only
        uint2 v = yq[(size_t)n * 16 + c];
        float2 fA = __half22float2(*(const __half2*)&v.x);
        float2 fB = __half22float2(*(const __half2*)&v.y);
        aA.x += fA.x; aA.y += fA.y; aB.x += fB.x; aB.y += fB.y;
    }
    const int dlim = min(dp, 64);
    for (int k = 0; k < dlim; k += 16) {
#pragma unroll
        for (int u = 0; u < 4; ++u) {
            int s = __shfl(idx, k + 4 * u + g, 64);
            uint2 v = yq[(size_t)s * 16 + c];
            float2 fA = __half22float2(*(const __half2*)&v.x);
            float2 fB = __half22float2(*(const __half2*)&v.y);
            aA.x += fA.x; aA.y += fA.y; aB.x += fB.x; aB.y += fB.y;
        }
    }
    for (int kk = 64; kk < dp; kk += 4) {      // rare deg>64 tail (padded, safe)
        int s = esrc[beg + kk + g];
        uint2 v = yq[(size_t)s * 16 + c];
        float2 fA = __half22float2(*(const __half2*)&v.x);
        float2 fB = __half22float2(*(const __half2*)&v.y);
        aA.x += fA.x; aA.y += fA.y; aB.x += fB.x; aB.y += fB.y;
    }
#pragma unroll
    for (int off = 16; off <= 32; off <<= 1) {   // fold 4 edge groups
        aA.x += __shfl_xor(aA.x, off, 64);
        aA.y += __shfl_xor(aA.y, off, 64);
        aB.x += __shfl_xor(aB.x, off, 64);
        aB.y += __shfl_xor(aB.y, off, 64);
    }
    if (g == 0) {
        float4 bb = ((const float4*)b1)[c];
        float d = dinv[n];
        float h0 = fmaxf(fmaf(d, aA.x, bb.x), 0.0f);
        float h1 = fmaxf(fmaf(d, aA.y, bb.y), 0.0f);
        float h2 = fmaxf(fmaf(d, aB.x, bb.z), 0.0f);
        float h3 = fmaxf(fmaf(d, aB.y, bb.w), 0.0f);
        __half2 p0 = __floats2half2_rn(h0, h1);
        __half2 p1 = __floats2half2_rn(h2, h3);
        hq[(size_t)n * 16 + c] = make_uint2(*(const unsigned*)&p0, *(const unsigned*)&p1);
    }
}

// zs[n][j] = fp16(dinv[n] * (h[n] @ W2)[j]), row stride 12 halves, [10..12)=0.
__global__ __launch_bounds__(256) void k_zs(
    const __half* __restrict__ h, const float* __restrict__ W2,
    const float* __restrict__ dinv, unsigned* __restrict__ zs_u, int n_nodes) {
    __shared__ unsigned zbuf[256 * PSU];   // 6 KB
    const int t = threadIdx.x;
    const int n0 = blockIdx.x * 256;
    const int n = n0 + t;
    if (n < n_nodes) {
        float acc[O];
#pragma unroll
        for (int j = 0; j < O; ++j) acc[j] = 0.f;
        const __half2* hr = (const __half2*)(h + (size_t)n * H);
#pragma unroll
        for (int k2 = 0; k2 < H / 2; ++k2) {
            float2 hv = __half22float2(hr[k2]);
#pragma unroll
            for (int j = 0; j < O; ++j) {
                acc[j] = fmaf(hv.x, W2[(2 * k2 + 0) * O + j], acc[j]);
                acc[j] = fmaf(hv.y, W2[(2 * k2 + 1) * O + j], acc[j]);
            }
        }
        float d = dinv[n];
#pragma unroll
        for (int q = 0; q < O / 2; ++q) {
            __half2 p = __floats2half2_rn(acc[2 * q] * d, acc[2 * q + 1] * d);
            zbuf[t * PSU + q] = *(const unsigned*)&p;
        }
        zbuf[t * PSU + 5] = 0u;   // zero pad uint
    }
    __syncthreads();
    int total = (min(n0 + 256, n_nodes) - n0) * PSU;
    unsigned* zo = zs_u + (size_t)n0 * PSU;
    for (int i = t; i < total; i += 256) zo[i] = zbuf[i];
}

// out[n][j] = dinv[n] * (zs[n][j] + sum_k zs[esrc[k]][j]) + b2[j]   (fp32 out)
// 8 lanes/node; lanes 5..7 read the zero pad uint -> no inner predicates.
__global__ __launch_bounds__(256) void k_gather2(
    const unsigned* __restrict__ zs_u, const int* __restrict__ rowbeg,
    const int* __restrict__ degp, const int* __restrict__ esrc,
    const float* __restrict__ dinv, const float* __restrict__ b2,
    float* __restrict__ out, int n_nodes) {
    const int l = threadIdx.x & 63;
    const int j = l & 7;
    const int sbase = l & ~7;
    const int jj = (j < 5) ? j : 5;         // pad uint is zero
    const int n = blockIdx.x * 32 + (threadIdx.x >> 3);
    if (n >= n_nodes) return;
    const int beg = rowbeg[n];
    const int dp = degp[n];
    unsigned v0 = zs_u[(size_t)n * PSU + jj];
    float2 acc = __half22float2(*(const __half2*)&v0);
    for (int k0 = 0; k0 < dp; k0 += 8) {
        int idx = esrc[beg + k0 + j];       // unpredicated (dp multiple of 16)
#pragma unroll
        for (int e = 0; e < 8; ++e) {
            int s = __shfl(idx, sbase + e, 64);
            unsigned v = zs_u[(size_t)s * PSU + jj];
            float2 f = __half22float2(*(const __half2*)&v);
            acc.x += f.x;
            acc.y += f.y;
        }
    }
    if (j < 5) {
        float2 bb = ((const float2*)b2)[j];
        float d = dinv[n];
        float2 o = make_float2(fmaf(d, acc.x, bb.x), fmaf(d, acc.y, bb.y));
        *(float2*)&out[(size_t)n * O + 2 * j] = o;
    }
}

static inline size_t align256(size_t v) { return (v + 255) & ~(size_t)255; }

extern "C" void kernel_launch(void* const* d_in, const int* in_sizes, int n_in,
                              void* d_out, int out_size, void* d_ws, size_t ws_size,
                              hipStream_t stream) {
    const float* x  = (const float*)d_in[0];
    const int*   ei = (const int*)d_in[1];
    const float* W1 = (const float*)d_in[2];
    const float* b1 = (const float*)d_in[3];
    const float* W2 = (const float*)d_in[4];
    const float* b2 = (const float*)d_in[5];
    float* out = (float*)d_out;

    const int N = in_sizes[0] / F;   // 100000
    const int E = in_sizes[1] / 2;   // 1600000
    const int* src = ei;
    const int* dst = ei + E;
    const int NBUK = (N + 511) >> 9;            // 196

    // Workspace (bytes): y[(N+1)*H fp16] | h-region[N*H fp16] (front aliased by
    // ebuf 9.63MB, consumed by k_bsort before h written; last 16KB = W1f) |
    // zs[(N+1)*PSU uints] | dinv[N] | rowbeg[N] | degp[N] | bcntg[256]
    // | esrc[NBUK*ESCAP + 64]
    char* base = (char*)d_ws;
    __half* y = (__half*)base;
    size_t ysz = align256((size_t)(N + 1) * H * 2);
    char* hreg = base + ysz;
    __half* h = (__half*)hreg;
    unsigned* ebuf = (unsigned*)hreg;                       // 9.63MB <= 12.78MB
    __half* W1f = (__half*)(hreg + (size_t)N * H * 2 - (size_t)F * H * 2);
    size_t hsz = align256((size_t)N * H * 2);
    char* zreg = hreg + hsz;
    unsigned* zs_u = (unsigned*)zreg;
    size_t zsz = align256((size_t)(N + 1) * PSU * 4);
    float* dinv = (float*)(zreg + zsz);
    int* rowbeg = (int*)(dinv + N);
    int* degp = rowbeg + N;
    int* bcntg = degp + N;
    int* esrc = bcntg + 256;

    const int nb_bin = (E + EPB - 1) / EPB;     // 391

    k_init<<<1 + F * H / 256, 256, 0, stream>>>(bcntg, W1, W1f,
                                                (unsigned*)(y + (size_t)N * H),
                                                zs_u + (size_t)N * PSU);
    k_bin<<<nb_bin, 256, 0, stream>>>(src, dst, bcntg, ebuf, E);
    k_bsort<<<NBUK, 256, 0, stream>>>(ebuf, bcntg, rowbeg, degp, dinv, esrc, N);
    k_gemm1<<<(N + 63) / 64, 256, 0, stream>>>(x, W1f, dinv, y, N);
    k_gather1<<<(N + 3) / 4, 256, 0, stream>>>((const uint2*)y, rowbeg, degp,
                                               esrc, dinv, b1, (uint2*)h, N);
    k_zs<<<(N + 255) / 256, 256, 0, stream>>>(h, W2, dinv, zs_u, N);
    k_gather2<<<(N + 31) / 32, 256, 0, stream>>>(zs_u, rowbeg, degp, esrc,
                                                 dinv, b2, out, N);
}